// Round 13
// baseline (167.104 us; speedup 1.0000x reference)
//
#include <hip/hip_runtime.h>
#include <hip/hip_bf16.h>
#include <math.h>

#define NHEADS 8
#define NTOK   1024
#define MTOK   2048

typedef __attribute__((ext_vector_type(8))) short  sh8;
typedef __attribute__((ext_vector_type(8))) __bf16 bf16x8;
typedef __attribute__((ext_vector_type(4))) float  f32x4;
typedef __attribute__((ext_vector_type(4))) unsigned int u32x4;

__device__ __forceinline__ short f2bf(float v) {
    return __builtin_bit_cast(short, __float2bfloat16(v));
}
__device__ __forceinline__ float bf2f(short v) {
    return __builtin_bit_cast(float, ((unsigned)(unsigned short)v) << 16);
}
__device__ __forceinline__ float ex2(float v) {
    return __builtin_amdgcn_exp2f(v);
}
__device__ __forceinline__ f32x4 mfma16(sh8 a, sh8 b, f32x4 c) {
    return __builtin_amdgcn_mfma_f32_16x16x32_bf16(
        __builtin_bit_cast(bf16x8, a), __builtin_bit_cast(bf16x8, b), c, 0, 0, 0);
}
__device__ __forceinline__ void aload16(void* lds, const void* g) {
    __builtin_amdgcn_global_load_lds(
        (const __attribute__((address_space(1))) unsigned int*)g,
        (__attribute__((address_space(3))) unsigned int*)lds, 16, 0, 0);
}

#define LOG2E 1.4426950408889634f

// ---------------- LayerNorm -> bf16 (optionally fuse resout = x + bias2) -------
template<bool FUSE>
__global__ __launch_bounds__(256) void ln_bf16(const float* __restrict__ x,
    const float* __restrict__ g, const float* __restrict__ bta, short* __restrict__ y,
    const float* __restrict__ bias2, float* __restrict__ resout)
{
    int row = blockIdx.x, t = threadIdx.x;
    const float* xr = x + (size_t)row * 512;
    float2 v = *reinterpret_cast<const float2*>(&xr[t*2]);
    float s = v.x + v.y, ss = v.x*v.x + v.y*v.y;
    #pragma unroll
    for (int m = 1; m < 64; m <<= 1) { s += __shfl_xor(s, m); ss += __shfl_xor(ss, m); }
    __shared__ float red[8];
    int wid = t >> 6, lane = t & 63;
    if (!lane) { red[wid] = s; red[4+wid] = ss; }
    __syncthreads();
    s = red[0]+red[1]+red[2]+red[3]; ss = red[4]+red[5]+red[6]+red[7];
    float mu = s*(1.f/512), var = ss*(1.f/512) - mu*mu, rs = rsqrtf(var + 1e-5f);
    float2 gg = *reinterpret_cast<const float2*>(&g[t*2]);
    float2 bb = *reinterpret_cast<const float2*>(&bta[t*2]);
    short2 o; o.x = f2bf((v.x-mu)*rs*gg.x + bb.x); o.y = f2bf((v.y-mu)*rs*gg.y + bb.y);
    *reinterpret_cast<short2*>(&y[(size_t)row*512 + t*2]) = o;
    if (FUSE) {
        float2 b2 = *reinterpret_cast<const float2*>(&bias2[t*2]);
        float2 ro = {v.x + b2.x, v.y + b2.y};
        *reinterpret_cast<float2*>(&resout[(size_t)row*512 + t*2]) = ro;
    }
}

// ---------------- merged: two fp32 W[K][N] -> bf16 W^T[N][K] transposes --------
__global__ __launch_bounds__(256) void wconv2x(
    const float* __restrict__ W0, short* __restrict__ WT0, int K0, int N0, int nb0,
    const float* __restrict__ W1, short* __restrict__ WT1, int K1, int N1)
{
    const float* W; short* WT; int K, N, bid;
    if ((int)blockIdx.x < nb0) { W = W0; WT = WT0; K = K0; N = N0; bid = blockIdx.x; }
    else                       { W = W1; WT = WT1; K = K1; N = N1; bid = blockIdx.x - nb0; }
    int nbx = N >> 5;
    int bn = (bid % nbx) * 32, bk = (bid / nbx) * 32;
    __shared__ float t[32][33];
    int c = threadIdx.x & 31, r8 = threadIdx.x >> 5;
    #pragma unroll
    for (int i = 0; i < 4; ++i) {
        int r = r8 + i*8;
        t[r][c] = W[(size_t)(bk + r)*N + bn + c];
    }
    __syncthreads();
    #pragma unroll
    for (int i = 0; i < 4; ++i) {
        int r = r8 + i*8;
        WT[(size_t)(bn + r)*K + bk + c] = f2bf(t[c][r]);
    }
}

// ---------------- prep: blocked rn table + blocked mask bits -------------------
// block = (b, qt16) -> 128 blocks. coords row staged in LDS.
// rnP[((bqt*16 + jt)*4 + n)*256 + lane*4 + r] = rn[q = qt*16 + (lane&15)]
//                                                 [k = jt*64 + n*16 + (lane>>4)*4 + r]
// mbP[(bqt*16 + jt)*16 + q] = ballot over 64 k of mask row
__global__ __launch_bounds__(256) void prep(const float* __restrict__ coords,
    const unsigned char* __restrict__ mask, short* __restrict__ rnP,
    unsigned long long* __restrict__ mbP)
{
    __shared__ float2 LC[1024];
    int bq = blockIdx.x;                 // b*64 + qt
    int b = bq >> 6, qt = bq & 63;
    int t = threadIdx.x;
    int w = t >> 6, lane = t & 63;
    int lr = lane & 15, lg = lane >> 4;

    #pragma unroll
    for (int i = 0; i < 4; ++i)
        LC[t*4 + i] = *reinterpret_cast<const float2*>(&coords[(size_t)(b*1024 + t*4 + i)*2]);
    __syncthreads();

    float2 qc = LC[qt*16 + lr];
    #pragma unroll
    for (int jt = 0; jt < 16; ++jt) {
        #pragma unroll
        for (int n = 0; n < 4; ++n) {
            short4 o;
            short* op = &o.x;
            #pragma unroll
            for (int r = 0; r < 4; ++r) {
                float2 kc = LC[jt*64 + n*16 + lg*4 + r];
                float dx = qc.x - kc.x, dy = qc.y - kc.y;
                op[r] = f2bf(sqrtf(dx*dx + dy*dy));
            }
            *reinterpret_cast<short4*>(&rnP[(size_t)(((bq*16 + jt)*4 + n)*256) + lane*4]) = o;
        }
    }

    // mask ballots: wave w handles jt = w*4 + (i>>4), q = i&15
    #pragma unroll
    for (int i = 0; i < 64; ++i) {
        int q = i & 15, jt = w*4 + (i >> 4);
        unsigned char v = mask[(size_t)(b*1024 + qt*16 + q)*NTOK + jt*64 + lane];
        unsigned long long bits = __ballot(v != 0);
        if (!lane) mbP[(size_t)(bq*16 + jt)*16 + q] = bits;
    }
}

// ---------------- bf16 MFMA GEMM, 64x64 tile, BK=64, 3-stage counted-vmcnt ----
// EPI: 0 bias; 1 bias+res (f32 out); 2 bias+gelu; 3 split-K atomicAdd (f32)
template<int EPI, bool OUTBF, bool BIAS_ROW, int SPLITK, bool QSC, int NT>
__global__ __launch_bounds__(256) void gemm64(
    const short* __restrict__ A, const short* __restrict__ BT,
    const float* __restrict__ bias, const float* __restrict__ res,
    void* __restrict__ Cout, int M, int N, int K, int nbx)
{
    __shared__ sh8 As8[3][512];
    __shared__ sh8 Bs8[3][512];
    int tid = threadIdx.x;
    int w = tid >> 6, lane = tid & 63, lr = lane & 15, lg = lane >> 4;
    int wr = w >> 1, wc = w & 1;
    int cpx = gridDim.x >> 3;
    int swz = (blockIdx.x & 7)*cpx + (blockIdx.x >> 3);
    int bx = swz % nbx, by = swz / nbx;
    int bm0 = by*64, bn0 = bx*64;
    int kbeg = (K / SPLITK) * blockIdx.z;

    f32x4 zero = {0.f,0.f,0.f,0.f};
    f32x4 acc[2][2];
    #pragma unroll
    for (int m = 0; m < 2; ++m)
        #pragma unroll
        for (int n = 0; n < 2; ++n) acc[m][n] = zero;

    #define STAGE(buf, k0) { \
        _Pragma("unroll") \
        for (int it = 0; it < 2; ++it) { \
            int s = tid + it*256; \
            int r = s >> 3, g = s & 7; \
            int ksw = (k0) + ((g ^ (r & 7)) << 3); \
            aload16(&As8[buf][s], A  + (size_t)(bm0 + r)*K + ksw); \
            aload16(&Bs8[buf][s], BT + (size_t)(bn0 + r)*K + ksw); \
        } }

    STAGE(0, kbeg)
    if (NT > 1) STAGE(1, kbeg + 64)

    #pragma unroll
    for (int t = 0; t < NT; ++t) {
        if (t + 1 < NT) asm volatile("s_waitcnt vmcnt(4)" ::: "memory");
        else            asm volatile("s_waitcnt vmcnt(0)" ::: "memory");
        __builtin_amdgcn_s_barrier();
        __builtin_amdgcn_sched_barrier(0);
        int buf = t % 3;
        sh8 af[2][2], bfv[2][2];
        #pragma unroll
        for (int m = 0; m < 2; ++m) {
            int R = wr*32 + m*16 + lr;
            #pragma unroll
            for (int s = 0; s < 2; ++s) af[m][s] = As8[buf][R*8 + ((s*4+lg) ^ (R & 7))];
        }
        #pragma unroll
        for (int n = 0; n < 2; ++n) {
            int R = wc*32 + n*16 + lr;
            #pragma unroll
            for (int s = 0; s < 2; ++s) bfv[n][s] = Bs8[buf][R*8 + ((s*4+lg) ^ (R & 7))];
        }
        if (t + 2 < NT) STAGE((t+2)%3, kbeg + (t+2)*64)
        #pragma unroll
        for (int m = 0; m < 2; ++m)
            #pragma unroll
            for (int n = 0; n < 2; ++n)
                #pragma unroll
                for (int s = 0; s < 2; ++s)
                    acc[m][n] = mfma16(af[m][s], bfv[n][s], acc[m][n]);
        asm volatile("s_waitcnt lgkmcnt(0)" ::: "memory");
    }
    #undef STAGE

    #pragma unroll
    for (int m = 0; m < 2; ++m) {
        #pragma unroll
        for (int n = 0; n < 2; ++n) {
            #pragma unroll
            for (int r = 0; r < 4; ++r) {
                int row = bm0 + wr*32 + m*16 + lg*4 + r;
                int col = bn0 + wc*32 + n*16 + lr;
                if (EPI == 3) {
                    atomicAdd((float*)Cout + (size_t)row*N + col, acc[m][n][r]);
                } else {
                    float v = acc[m][n][r] + (BIAS_ROW ? bias[row] : bias[col]);
                    if (QSC && col < 512) v *= (0.125f * LOG2E);
                    if (EPI == 1) v += res[(size_t)row*N + col];
                    if (EPI == 2) v = 0.5f * v * (1.0f + erff(v * 0.70710678f));
                    if (OUTBF) ((short*)Cout)[(size_t)row*N + col] = f2bf(v);
                    else       ((float*)Cout)[(size_t)row*N + col] = v;
                }
            }
        }
    }
}

// ---------------- LDS-staged MFMA flash attention, KV-split x4, swapped QK ----
// rn/mask now read from lane-blocked tables: fully coalesced.
__global__ __launch_bounds__(256) void attn_reg(
    const short* __restrict__ qk, const short* __restrict__ vt,
    const short* __restrict__ rnP, const unsigned long long* __restrict__ mbP,
    const float* __restrict__ w_edge, short* __restrict__ OpA,
    short* __restrict__ OpB, float* __restrict__ ml)
{
    __shared__ sh8 Ks8[2][512];   // [64 k][8 slots 16B] swizzled
    __shared__ sh8 Vs8[2][512];   // [64 d][8 slots 16B] swizzled

    int cpx = gridDim.x >> 3;     // 1024 blocks -> 128
    int swz = (blockIdx.x & 7)*cpx + (blockIdx.x >> 3);
    int w = threadIdx.x >> 6, lane = threadIdx.x & 63;
    int lr = lane & 15, lg = lane >> 4;
    int qb = swz & 15;            // q block of 64 rows
    int h  = (swz >> 4) & 7;
    int b  = (swz >> 7) & 1;
    int ks = swz >> 8;            // KV split 0..3

    const int q0 = qb*64 + w*16;
    const int qrow0 = b*NTOK + q0;
    const int jt0 = ks*4;
    const int bqt = b*64 + qb*4 + w;    // prep's (b, qt16) block index

    sh8 qf[2];   // Q[q=lr][d=s*32+lg*8..] — MFMA B operand
    #pragma unroll
    for (int s = 0; s < 2; ++s)
        qf[s] = *reinterpret_cast<const sh8*>(qk + (size_t)(qrow0 + lr)*1024 + h*64 + s*32 + lg*8);

    float we2l = w_edge[2*NHEADS + h] * LOG2E;

    float m_i = -1e30f, l_lane = 0.f;   // per-lane: stats for q = lr
    f32x4 zero = {0.f,0.f,0.f,0.f};
    f32x4 accO[4];
    #pragma unroll
    for (int n = 0; n < 4; ++n) accO[n] = zero;

    const short* kbase = qk + 512 + h*64;
    const short* vbase = vt + (size_t)h*64*2048 + b*NTOK;
    int sr = threadIdx.x >> 3, sg = threadIdx.x & 7;
    int sx = (sg ^ (sr & 7)) << 3;

    #define ASTAGE(bf, jt) { \
        aload16(&Ks8[bf][threadIdx.x],       kbase + (size_t)(b*NTOK + (jt)*64 + sr)*1024 + sx); \
        aload16(&Ks8[bf][threadIdx.x + 256], kbase + (size_t)(b*NTOK + (jt)*64 + sr + 32)*1024 + sx); \
        aload16(&Vs8[bf][threadIdx.x],       vbase + (size_t)sr*2048 + (jt)*64 + sx); \
        aload16(&Vs8[bf][threadIdx.x + 256], vbase + (size_t)(sr + 32)*2048 + (jt)*64 + sx); \
    }

    short4 rn_reg[2][4];
    unsigned long long mr_reg[2];
    #define RMLOAD(bf, jt) { \
        _Pragma("unroll") \
        for (int n = 0; n < 4; ++n) \
            rn_reg[bf][n] = *reinterpret_cast<const short4*>( \
                &rnP[(size_t)(((bqt*16 + (jt))*4 + n)*256) + lane*4]); \
        mr_reg[bf] = mbP[(size_t)(bqt*16 + (jt))*16 + lr]; \
    }

    ASTAGE(0, jt0)
    RMLOAD(0, jt0)

    #pragma unroll
    for (int t = 0; t < 4; ++t) {
        if (t == 0) asm volatile("s_waitcnt vmcnt(0)" ::: "memory");
        else        asm volatile("s_waitcnt vmcnt(5)" ::: "memory");
        __builtin_amdgcn_s_barrier();
        __builtin_amdgcn_sched_barrier(0);
        int buf = t & 1;

        if (t + 1 < 4) {
            ASTAGE(buf ^ 1, jt0 + t + 1)
            RMLOAD(buf ^ 1, jt0 + t + 1)
        }

        // S^T = K Q^T: lane holds S[k = 16n + 4lg + r][q = lr]
        f32x4 Sv[4];
        #pragma unroll
        for (int n = 0; n < 4; ++n) {
            int kcol = n*16 + lr;
            sh8 k0v = Ks8[buf][kcol*8 + (lg       ^ (kcol & 7))];
            sh8 k1v = Ks8[buf][kcol*8 + ((4 + lg) ^ (kcol & 7))];
            Sv[n] = mfma16(k1v, qf[1], mfma16(k0v, qf[0], zero));
        }

        // radial bias (log2 domain); rn_reg[n].r matches S[k=16n+4lg+r][q=lr]
        #pragma unroll
        for (int n = 0; n < 4; ++n) {
            short4 rn4 = rn_reg[buf][n];
            Sv[n][0] = fmaf(bf2f(rn4.x), we2l, Sv[n][0]);
            Sv[n][1] = fmaf(bf2f(rn4.y), we2l, Sv[n][1]);
            Sv[n][2] = fmaf(bf2f(rn4.z), we2l, Sv[n][2]);
            Sv[n][3] = fmaf(bf2f(rn4.w), we2l, Sv[n][3]);
        }

        // lane-local max + 2-shfl reduce
        float mx = Sv[0][0];
        #pragma unroll
        for (int n = 0; n < 4; ++n)
            #pragma unroll
            for (int r = 0; r < 4; ++r) mx = fmaxf(mx, Sv[n][r]);
        mx = fmaxf(mx, __shfl_xor(mx, 16));
        mx = fmaxf(mx, __shfl_xor(mx, 32));
        float mnew = fmaxf(m_i, mx);
        float f = ex2(m_i - mnew);
        m_i = mnew;

        // exp, post-exp mask-zero, lane-partial sum, bf16 pack
        unsigned long long mr = mr_reg[buf];
        float ps = 0.f;
        unsigned pk[8];
        #pragma unroll
        for (int n = 0; n < 4; ++n) {
            float p_[4];
            #pragma unroll
            for (int r = 0; r < 4; ++r) {
                float p = ex2(Sv[n][r] - mnew);
                p = ((mr >> (n*16 + lg*4 + r)) & 1ull) ? 0.f : p;
                ps += p;
                p_[r] = p;
            }
            pk[2*n]   = ((unsigned)(unsigned short)f2bf(p_[1]) << 16) | (unsigned short)f2bf(p_[0]);
            pk[2*n+1] = ((unsigned)(unsigned short)f2bf(p_[3]) << 16) | (unsigned short)f2bf(p_[2]);
        }
        l_lane = l_lane * f + ps;

        // PA fragments via shfl
        int src0 = lr + ((lg & 1) << 5);
        int src1 = src0 + 16;
        sh8 pa[2];
        #pragma unroll
        for (int s = 0; s < 2; ++s) {
            int ns = 2*s + (lg >> 1);
            u32x4 dv;
            dv.x = (unsigned)__shfl((int)pk[2*ns],   src0);
            dv.y = (unsigned)__shfl((int)pk[2*ns+1], src0);
            dv.z = (unsigned)__shfl((int)pk[2*ns],   src1);
            dv.w = (unsigned)__shfl((int)pk[2*ns+1], src1);
            pa[s] = __builtin_bit_cast(sh8, dv);
        }

        // broadcast rescale into accO layout
        float fb[4];
        #pragma unroll
        for (int r = 0; r < 4; ++r) fb[r] = __shfl(f, lg*4 + r);
        #pragma unroll
        for (int n = 0; n < 4; ++n)
            #pragma unroll
            for (int r = 0; r < 4; ++r) accO[n][r] *= fb[r];

        // PV
        #pragma unroll
        for (int n = 0; n < 4; ++n) {
            int dcol = n*16 + lr;
            sh8 v0 = Vs8[buf][dcol*8 + (lg       ^ (dcol & 7))];
            sh8 v1 = Vs8[buf][dcol*8 + ((4 + lg) ^ (dcol & 7))];
            accO[n] = mfma16(pa[1], v1, mfma16(pa[0], v0, accO[n]));
        }

        asm volatile("s_waitcnt lgkmcnt(0)" ::: "memory");
    }
    #undef ASTAGE
    #undef RMLOAD

    l_lane += __shfl_xor(l_lane, 16);
    l_lane += __shfl_xor(l_lane, 32);

    short* Op = (ks < 2) ? OpA : OpB;
    #pragma unroll
    for (int r = 0; r < 4; ++r) {
        size_t row = (size_t)((ks & 1)*MTOK + qrow0 + lg*4 + r);
        #pragma unroll
        for (int n = 0; n < 4; ++n)
            Op[row*512 + h*64 + n*16 + lr] = f2bf(accO[n][r]);
    }
    if (lg == 0) {
        size_t mrow = (size_t)(ks*MTOK + qrow0 + lr);
        ml[(mrow*NHEADS + h)*2 + 0] = m_i;
        ml[(mrow*NHEADS + h)*2 + 1] = l_lane;
    }
}

// ---------------- combine 4 KV-split partials -> bf16 O ----------------
__global__ __launch_bounds__(256) void attn_combine4(const short* __restrict__ OpA,
    const short* __restrict__ OpB, const float* __restrict__ ml,
    short* __restrict__ ob)
{
    int idx = blockIdx.x*256 + threadIdx.x;     // MTOK*128 threads
    int tok = idx >> 7, dd = (idx & 127) * 4;
    int h = dd >> 6;
    float m[4], l[4];
    #pragma unroll
    for (int s = 0; s < 4; ++s) {
        m[s] = ml[(((size_t)s*MTOK + tok)*NHEADS + h)*2 + 0];
        l[s] = ml[(((size_t)s*MTOK + tok)*NHEADS + h)*2 + 1];
    }
    float mm = fmaxf(fmaxf(m[0], m[1]), fmaxf(m[2], m[3]));
    float wsum = 0.f, a0 = 0.f, a1 = 0.f, a2 = 0.f, a3 = 0.f;
    #pragma unroll
    for (int s = 0; s < 4; ++s) {
        float wv = ex2(m[s] - mm);
        wsum += wv * l[s];
        const short* Op = (s < 2) ? OpA : OpB;
        short4 p = *reinterpret_cast<const short4*>(&Op[((size_t)((s&1)*MTOK) + tok)*512 + dd]);
        a0 += bf2f(p.x)*wv; a1 += bf2f(p.y)*wv;
        a2 += bf2f(p.z)*wv; a3 += bf2f(p.w)*wv;
    }
    float inv = 1.f / wsum;
    short4 o;
    o.x = f2bf(a0*inv); o.y = f2bf(a1*inv);
    o.z = f2bf(a2*inv); o.w = f2bf(a3*inv);
    *reinterpret_cast<short4*>(&ob[(size_t)tok*512 + dd]) = o;
}

// -------------------------------------------------------------------------------
extern "C" void kernel_launch(void* const* d_in, const int* in_sizes, int n_in,
                              void* d_out, int out_size, void* d_ws, size_t ws_size,
                              hipStream_t stream)
{
    const float* x      = (const float*)d_in[0];
    const float* coords = (const float*)d_in[1];
    const unsigned char* mask = (const unsigned char*)d_in[2];
    const float* ln1_g = (const float*)d_in[3];
    const float* ln1_b = (const float*)d_in[4];
    const float* w_qkv = (const float*)d_in[5];
    const float* b_qkv = (const float*)d_in[6];
    const float* w_edge= (const float*)d_in[7];
    const float* w_out = (const float*)d_in[8];
    const float* b_out = (const float*)d_in[9];
    const float* ln2_g = (const float*)d_in[10];
    const float* ln2_b = (const float*)d_in[11];
    const float* w1    = (const float*)d_in[12];
    const float* b1    = (const float*)d_in[13];
    const float* w2    = (const float*)d_in[14];
    const float* b2    = (const float*)d_in[15];
    float* out = (float*)d_out;

    char* W = (char*)d_ws;
    const size_t MB = 1024*1024;
    float* x1    = (float*)(W);                    // [0,4M) f32 (written by outproj)
    short* qk    = (short*)(W + 4*MB);             // [4M,8M)
    short* vtb   = (short*)(W + 8*MB);             // [8M,10M)
    short* woutT = (short*)(W + 10*MB);            // [10M,10.5M)
    short* xln   = (short*)(W + 10*MB + 512*1024); // [10.5M,12.5M)  (later y)
    short* wqkvT = (short*)(W + 12*MB + 512*1024); // [12.5M,14M)
    short* OpB   = (short*)(W + 10*MB + 512*1024); // [10.5M,14.5M) over dead xln/wqkvT
    short* OpA   = (short*)(W + 14*MB + 512*1024); // [14.5M,18.5M)
    short* rnP   = (short*)(W + 18*MB + 512*1024); // [18.5M,22.5M) bf16 blocked
    float* mlp   = (float*)(W + 22*MB + 512*1024); // [22.5M,23M) 4x2048x8x2 f32
    unsigned long long* mbP = (unsigned long long*)(W + 23*MB); // [23M,23.25M) blocked
    short* ob    = (short*)(W + 6*MB);             // [6M,8M)  (qk dead after attn)
    short* y     = xln;                            // [10.5M,12.5M) (OpB dead)
    short* w1T   = (short*)(W + 4*MB);             // [4M,6M)  (qk dead)
    short* w2T   = (short*)(W + 8*MB);             // [8M,10M) (vtb dead)
    short* hid   = (short*)(W + 14*MB + 512*1024); // [14.5M,22.5M) (OpA/rnP dead)

    // ---- phase 1 ----
    prep<<<dim3(128,1,1), 256, 0, stream>>>(coords, mask, rnP, mbP);
    wconv2x<<<dim3(1024,1,1), 256, 0, stream>>>(w_qkv, wqkvT, 512, 1536, 768,
                                                w_out, woutT, 512, 512);
    ln_bf16<false><<<MTOK, 256, 0, stream>>>(x, ln1_g, ln1_b, xln, nullptr, nullptr);
    gemm64<0,true,false,1,true,8><<<dim3(512,1,1), 256, 0, stream>>>(
        xln, wqkvT, b_qkv, nullptr, qk, MTOK, 1024, 512, 16);
    gemm64<0,true,true,1,false,8><<<dim3(256,1,1), 256, 0, stream>>>(
        wqkvT + (size_t)1024*512, xln, b_qkv + 1024, nullptr, vtb, 512, MTOK, 512, 32);
    attn_reg<<<dim3(1024,1,1), 256, 0, stream>>>(qk, vtb, rnP, mbP, w_edge, OpA, OpB, mlp);
    attn_combine4<<<dim3(1024,1,1), 256, 0, stream>>>(OpA, OpB, mlp, ob);
    // x1 = ob @ w_out + b_out + x   (no split-K, no atomics)
    gemm64<1,false,false,1,false,8><<<dim3(256,1,1), 256, 0, stream>>>(
        ob, woutT, b_out, x, x1, MTOK, 512, 512, 8);
    // ---- phase 2 ----
    wconv2x<<<dim3(2048,1,1), 256, 0, stream>>>(w1, w1T, 512, 2048, 1024,
                                                w2, w2T, 2048, 512);
    ln_bf16<true><<<MTOK, 256, 0, stream>>>(x1, ln2_g, ln2_b, y, b2, out);
    gemm64<2,true,false,1,false,8><<<dim3(1024,1,1), 256, 0, stream>>>(
        y, w1T, b1, nullptr, hid, MTOK, 2048, 512, 32);
    // out += hid @ w2   (split-K=2 atomics)
    gemm64<3,false,false,2,false,16><<<dim3(256,1,2), 256, 0, stream>>>(
        hid, w2T, nullptr, nullptr, out, MTOK, 512, 2048, 8);
}

// Round 14
// 92.837 us; speedup vs baseline: 1.8000x; 1.8000x over previous
//
#include <hip/hip_runtime.h>
#include <hip/hip_bf16.h>
#include <math.h>

#define NHEADS 8
#define NTOK   1024
#define MTOK   2048

typedef __attribute__((ext_vector_type(8))) short  sh8;
typedef __attribute__((ext_vector_type(8))) __bf16 bf16x8;
typedef __attribute__((ext_vector_type(4))) float  f32x4;
typedef __attribute__((ext_vector_type(4))) unsigned int u32x4;

__device__ __forceinline__ short f2bf(float v) {
    return __builtin_bit_cast(short, __float2bfloat16(v));
}
__device__ __forceinline__ float bf2f(short v) {
    return __builtin_bit_cast(float, ((unsigned)(unsigned short)v) << 16);
}
__device__ __forceinline__ float ex2(float v) {
    return __builtin_amdgcn_exp2f(v);
}
__device__ __forceinline__ f32x4 mfma16(sh8 a, sh8 b, f32x4 c) {
    return __builtin_amdgcn_mfma_f32_16x16x32_bf16(
        __builtin_bit_cast(bf16x8, a), __builtin_bit_cast(bf16x8, b), c, 0, 0, 0);
}
__device__ __forceinline__ void aload16(void* lds, const void* g) {
    __builtin_amdgcn_global_load_lds(
        (const __attribute__((address_space(1))) unsigned int*)g,
        (__attribute__((address_space(3))) unsigned int*)lds, 16, 0, 0);
}

#define LOG2E 1.4426950408889634f

// ---------------- LayerNorm -> bf16 (optionally fuse resout = x + bias2) -------
template<bool FUSE>
__global__ __launch_bounds__(256) void ln_bf16(const float* __restrict__ x,
    const float* __restrict__ g, const float* __restrict__ bta, short* __restrict__ y,
    const float* __restrict__ bias2, float* __restrict__ resout)
{
    int row = blockIdx.x, t = threadIdx.x;
    const float* xr = x + (size_t)row * 512;
    float2 v = *reinterpret_cast<const float2*>(&xr[t*2]);
    float s = v.x + v.y, ss = v.x*v.x + v.y*v.y;
    #pragma unroll
    for (int m = 1; m < 64; m <<= 1) { s += __shfl_xor(s, m); ss += __shfl_xor(ss, m); }
    __shared__ float red[8];
    int wid = t >> 6, lane = t & 63;
    if (!lane) { red[wid] = s; red[4+wid] = ss; }
    __syncthreads();
    s = red[0]+red[1]+red[2]+red[3]; ss = red[4]+red[5]+red[6]+red[7];
    float mu = s*(1.f/512), var = ss*(1.f/512) - mu*mu, rs = rsqrtf(var + 1e-5f);
    float2 gg = *reinterpret_cast<const float2*>(&g[t*2]);
    float2 bb = *reinterpret_cast<const float2*>(&bta[t*2]);
    short2 o; o.x = f2bf((v.x-mu)*rs*gg.x + bb.x); o.y = f2bf((v.y-mu)*rs*gg.y + bb.y);
    *reinterpret_cast<short2*>(&y[(size_t)row*512 + t*2]) = o;
    if (FUSE) {
        float2 b2 = *reinterpret_cast<const float2*>(&bias2[t*2]);
        float2 ro = {v.x + b2.x, v.y + b2.y};
        *reinterpret_cast<float2*>(&resout[(size_t)row*512 + t*2]) = ro;
    }
}

// ---------------- merged: two fp32 W[K][N] -> bf16 W^T[N][K] transposes --------
__global__ __launch_bounds__(256) void wconv2x(
    const float* __restrict__ W0, short* __restrict__ WT0, int K0, int N0, int nb0,
    const float* __restrict__ W1, short* __restrict__ WT1, int K1, int N1)
{
    const float* W; short* WT; int K, N, bid;
    if ((int)blockIdx.x < nb0) { W = W0; WT = WT0; K = K0; N = N0; bid = blockIdx.x; }
    else                       { W = W1; WT = WT1; K = K1; N = N1; bid = blockIdx.x - nb0; }
    int nbx = N >> 5;
    int bn = (bid % nbx) * 32, bk = (bid / nbx) * 32;
    __shared__ float t[32][33];
    int c = threadIdx.x & 31, r8 = threadIdx.x >> 5;
    #pragma unroll
    for (int i = 0; i < 4; ++i) {
        int r = r8 + i*8;
        t[r][c] = W[(size_t)(bk + r)*N + bn + c];
    }
    __syncthreads();
    #pragma unroll
    for (int i = 0; i < 4; ++i) {
        int r = r8 + i*8;
        WT[(size_t)(bn + r)*K + bk + c] = f2bf(t[c][r]);
    }
}

// ---------------- prep: blocked rn table + blocked mask bits -------------------
// block = (bqt, jt) -> 2048 blocks. wave w computes the n=w slice (no redundancy).
// rnP[((bqt*16 + jt)*4 + n)*256 + lane*4 + r] = rn[q = qt*16 + (lane&15)]
//                                                 [k = jt*64 + n*16 + (lane>>4)*4 + r]
// mbP[(bqt*16 + jt)*16 + q] = ballot over 64 k of mask row q
__global__ __launch_bounds__(256) void prep(const float* __restrict__ coords,
    const unsigned char* __restrict__ mask, short* __restrict__ rnP,
    unsigned long long* __restrict__ mbP)
{
    __shared__ float2 kc_s[64];
    __shared__ float2 qc_s[16];
    int bid = blockIdx.x;                // bqt*16 + jt
    int bqt = bid >> 4, jt = bid & 15;
    int b = bqt >> 6, qt = bqt & 63;
    int t = threadIdx.x, w = t >> 6, lane = t & 63;
    int lr = lane & 15, lg = lane >> 4;

    if (t < 64)            kc_s[t]      = *reinterpret_cast<const float2*>(&coords[(size_t)(b*1024 + jt*64 + t)*2]);
    else if (t < 80)       qc_s[t - 64] = *reinterpret_cast<const float2*>(&coords[(size_t)(b*1024 + qt*16 + (t - 64))*2]);
    __syncthreads();

    // rn slice n = w: one coalesced 512B write per wave
    float2 qc = qc_s[lr];
    short4 o;
    short* op = &o.x;
    #pragma unroll
    for (int r = 0; r < 4; ++r) {
        float2 kc = kc_s[w*16 + lg*4 + r];
        float dx = qc.x - kc.x, dy = qc.y - kc.y;
        op[r] = f2bf(sqrtf(dx*dx + dy*dy));
    }
    *reinterpret_cast<short4*>(&rnP[(size_t)((bid*4 + w)*256) + lane*4]) = o;

    // mask ballots: wave w handles q = w*4 + i
    #pragma unroll
    for (int i = 0; i < 4; ++i) {
        int q = w*4 + i;
        unsigned char v = mask[(size_t)(b*1024 + qt*16 + q)*NTOK + jt*64 + lane];
        unsigned long long bits = __ballot(v != 0);
        if (!lane) mbP[(size_t)bid*16 + q] = bits;
    }
}

// ---------------- bf16 MFMA GEMM, 64x64 tile, BK=64, 3-stage counted-vmcnt ----
// EPI: 0 bias; 1 bias+res (f32 out); 2 bias+gelu; 3 split-K atomicAdd (f32)
template<int EPI, bool OUTBF, bool BIAS_ROW, int SPLITK, bool QSC, int NT>
__global__ __launch_bounds__(256) void gemm64(
    const short* __restrict__ A, const short* __restrict__ BT,
    const float* __restrict__ bias, const float* __restrict__ res,
    void* __restrict__ Cout, int M, int N, int K, int nbx)
{
    __shared__ sh8 As8[3][512];
    __shared__ sh8 Bs8[3][512];
    int tid = threadIdx.x;
    int w = tid >> 6, lane = tid & 63, lr = lane & 15, lg = lane >> 4;
    int wr = w >> 1, wc = w & 1;
    int cpx = gridDim.x >> 3;
    int swz = (blockIdx.x & 7)*cpx + (blockIdx.x >> 3);
    int bx = swz % nbx, by = swz / nbx;
    int bm0 = by*64, bn0 = bx*64;
    int kbeg = (K / SPLITK) * blockIdx.z;

    f32x4 zero = {0.f,0.f,0.f,0.f};
    f32x4 acc[2][2];
    #pragma unroll
    for (int m = 0; m < 2; ++m)
        #pragma unroll
        for (int n = 0; n < 2; ++n) acc[m][n] = zero;

    #define STAGE(buf, k0) { \
        _Pragma("unroll") \
        for (int it = 0; it < 2; ++it) { \
            int s = tid + it*256; \
            int r = s >> 3, g = s & 7; \
            int ksw = (k0) + ((g ^ (r & 7)) << 3); \
            aload16(&As8[buf][s], A  + (size_t)(bm0 + r)*K + ksw); \
            aload16(&Bs8[buf][s], BT + (size_t)(bn0 + r)*K + ksw); \
        } }

    STAGE(0, kbeg)
    if (NT > 1) STAGE(1, kbeg + 64)

    #pragma unroll
    for (int t = 0; t < NT; ++t) {
        if (t + 1 < NT) asm volatile("s_waitcnt vmcnt(4)" ::: "memory");
        else            asm volatile("s_waitcnt vmcnt(0)" ::: "memory");
        __builtin_amdgcn_s_barrier();
        __builtin_amdgcn_sched_barrier(0);
        int buf = t % 3;
        sh8 af[2][2], bfv[2][2];
        #pragma unroll
        for (int m = 0; m < 2; ++m) {
            int R = wr*32 + m*16 + lr;
            #pragma unroll
            for (int s = 0; s < 2; ++s) af[m][s] = As8[buf][R*8 + ((s*4+lg) ^ (R & 7))];
        }
        #pragma unroll
        for (int n = 0; n < 2; ++n) {
            int R = wc*32 + n*16 + lr;
            #pragma unroll
            for (int s = 0; s < 2; ++s) bfv[n][s] = Bs8[buf][R*8 + ((s*4+lg) ^ (R & 7))];
        }
        if (t + 2 < NT) STAGE((t+2)%3, kbeg + (t+2)*64)
        #pragma unroll
        for (int m = 0; m < 2; ++m)
            #pragma unroll
            for (int n = 0; n < 2; ++n)
                #pragma unroll
                for (int s = 0; s < 2; ++s)
                    acc[m][n] = mfma16(af[m][s], bfv[n][s], acc[m][n]);
        asm volatile("s_waitcnt lgkmcnt(0)" ::: "memory");
    }
    #undef STAGE

    #pragma unroll
    for (int m = 0; m < 2; ++m) {
        #pragma unroll
        for (int n = 0; n < 2; ++n) {
            #pragma unroll
            for (int r = 0; r < 4; ++r) {
                int row = bm0 + wr*32 + m*16 + lg*4 + r;
                int col = bn0 + wc*32 + n*16 + lr;
                if (EPI == 3) {
                    atomicAdd((float*)Cout + (size_t)row*N + col, acc[m][n][r]);
                } else {
                    float v = acc[m][n][r] + (BIAS_ROW ? bias[row] : bias[col]);
                    if (QSC && col < 512) v *= (0.125f * LOG2E);
                    if (EPI == 1) v += res[(size_t)row*N + col];
                    if (EPI == 2) v = 0.5f * v * (1.0f + erff(v * 0.70710678f));
                    if (OUTBF) ((short*)Cout)[(size_t)row*N + col] = f2bf(v);
                    else       ((float*)Cout)[(size_t)row*N + col] = v;
                }
            }
        }
    }
}

// ---------------- LDS-staged MFMA flash attention, KV-split x4, swapped QK ----
// rn/mask read from lane-blocked tables: fully coalesced.
__global__ __launch_bounds__(256) void attn_reg(
    const short* __restrict__ qk, const short* __restrict__ vt,
    const short* __restrict__ rnP, const unsigned long long* __restrict__ mbP,
    const float* __restrict__ w_edge, short* __restrict__ OpA,
    short* __restrict__ OpB, float* __restrict__ ml)
{
    __shared__ sh8 Ks8[2][512];   // [64 k][8 slots 16B] swizzled
    __shared__ sh8 Vs8[2][512];   // [64 d][8 slots 16B] swizzled

    int cpx = gridDim.x >> 3;     // 1024 blocks -> 128
    int swz = (blockIdx.x & 7)*cpx + (blockIdx.x >> 3);
    int w = threadIdx.x >> 6, lane = threadIdx.x & 63;
    int lr = lane & 15, lg = lane >> 4;
    int qb = swz & 15;            // q block of 64 rows
    int h  = (swz >> 4) & 7;
    int b  = (swz >> 7) & 1;
    int ks = swz >> 8;            // KV split 0..3

    const int q0 = qb*64 + w*16;
    const int qrow0 = b*NTOK + q0;
    const int jt0 = ks*4;
    const int bqt = b*64 + qb*4 + w;    // prep's (b, qt16) block index

    sh8 qf[2];   // Q[q=lr][d=s*32+lg*8..] — MFMA B operand
    #pragma unroll
    for (int s = 0; s < 2; ++s)
        qf[s] = *reinterpret_cast<const sh8*>(qk + (size_t)(qrow0 + lr)*1024 + h*64 + s*32 + lg*8);

    float we2l = w_edge[2*NHEADS + h] * LOG2E;

    float m_i = -1e30f, l_lane = 0.f;   // per-lane: stats for q = lr
    f32x4 zero = {0.f,0.f,0.f,0.f};
    f32x4 accO[4];
    #pragma unroll
    for (int n = 0; n < 4; ++n) accO[n] = zero;

    const short* kbase = qk + 512 + h*64;
    const short* vbase = vt + (size_t)h*64*2048 + b*NTOK;
    int sr = threadIdx.x >> 3, sg = threadIdx.x & 7;
    int sx = (sg ^ (sr & 7)) << 3;

    #define ASTAGE(bf, jt) { \
        aload16(&Ks8[bf][threadIdx.x],       kbase + (size_t)(b*NTOK + (jt)*64 + sr)*1024 + sx); \
        aload16(&Ks8[bf][threadIdx.x + 256], kbase + (size_t)(b*NTOK + (jt)*64 + sr + 32)*1024 + sx); \
        aload16(&Vs8[bf][threadIdx.x],       vbase + (size_t)sr*2048 + (jt)*64 + sx); \
        aload16(&Vs8[bf][threadIdx.x + 256], vbase + (size_t)(sr + 32)*2048 + (jt)*64 + sx); \
    }

    short4 rn_reg[2][4];
    unsigned long long mr_reg[2];
    #define RMLOAD(bf, jt) { \
        _Pragma("unroll") \
        for (int n = 0; n < 4; ++n) \
            rn_reg[bf][n] = *reinterpret_cast<const short4*>( \
                &rnP[(size_t)(((bqt*16 + (jt))*4 + n)*256) + lane*4]); \
        mr_reg[bf] = mbP[(size_t)(bqt*16 + (jt))*16 + lr]; \
    }

    ASTAGE(0, jt0)
    RMLOAD(0, jt0)

    #pragma unroll
    for (int t = 0; t < 4; ++t) {
        if (t == 0) asm volatile("s_waitcnt vmcnt(0)" ::: "memory");
        else        asm volatile("s_waitcnt vmcnt(5)" ::: "memory");
        __builtin_amdgcn_s_barrier();
        __builtin_amdgcn_sched_barrier(0);
        int buf = t & 1;

        if (t + 1 < 4) {
            ASTAGE(buf ^ 1, jt0 + t + 1)
            RMLOAD(buf ^ 1, jt0 + t + 1)
        }

        // S^T = K Q^T: lane holds S[k = 16n + 4lg + r][q = lr]
        f32x4 Sv[4];
        #pragma unroll
        for (int n = 0; n < 4; ++n) {
            int kcol = n*16 + lr;
            sh8 k0v = Ks8[buf][kcol*8 + (lg       ^ (kcol & 7))];
            sh8 k1v = Ks8[buf][kcol*8 + ((4 + lg) ^ (kcol & 7))];
            Sv[n] = mfma16(k1v, qf[1], mfma16(k0v, qf[0], zero));
        }

        // radial bias (log2 domain)
        #pragma unroll
        for (int n = 0; n < 4; ++n) {
            short4 rn4 = rn_reg[buf][n];
            Sv[n][0] = fmaf(bf2f(rn4.x), we2l, Sv[n][0]);
            Sv[n][1] = fmaf(bf2f(rn4.y), we2l, Sv[n][1]);
            Sv[n][2] = fmaf(bf2f(rn4.z), we2l, Sv[n][2]);
            Sv[n][3] = fmaf(bf2f(rn4.w), we2l, Sv[n][3]);
        }

        // lane-local max + 2-shfl reduce
        float mx = Sv[0][0];
        #pragma unroll
        for (int n = 0; n < 4; ++n)
            #pragma unroll
            for (int r = 0; r < 4; ++r) mx = fmaxf(mx, Sv[n][r]);
        mx = fmaxf(mx, __shfl_xor(mx, 16));
        mx = fmaxf(mx, __shfl_xor(mx, 32));
        float mnew = fmaxf(m_i, mx);
        float f = ex2(m_i - mnew);
        m_i = mnew;

        // exp, post-exp mask-zero, lane-partial sum, bf16 pack
        unsigned long long mr = mr_reg[buf];
        float ps = 0.f;
        unsigned pk[8];
        #pragma unroll
        for (int n = 0; n < 4; ++n) {
            float p_[4];
            #pragma unroll
            for (int r = 0; r < 4; ++r) {
                float p = ex2(Sv[n][r] - mnew);
                p = ((mr >> (n*16 + lg*4 + r)) & 1ull) ? 0.f : p;
                ps += p;
                p_[r] = p;
            }
            pk[2*n]   = ((unsigned)(unsigned short)f2bf(p_[1]) << 16) | (unsigned short)f2bf(p_[0]);
            pk[2*n+1] = ((unsigned)(unsigned short)f2bf(p_[3]) << 16) | (unsigned short)f2bf(p_[2]);
        }
        l_lane = l_lane * f + ps;

        // PA fragments via shfl
        int src0 = lr + ((lg & 1) << 5);
        int src1 = src0 + 16;
        sh8 pa[2];
        #pragma unroll
        for (int s = 0; s < 2; ++s) {
            int ns = 2*s + (lg >> 1);
            u32x4 dv;
            dv.x = (unsigned)__shfl((int)pk[2*ns],   src0);
            dv.y = (unsigned)__shfl((int)pk[2*ns+1], src0);
            dv.z = (unsigned)__shfl((int)pk[2*ns],   src1);
            dv.w = (unsigned)__shfl((int)pk[2*ns+1], src1);
            pa[s] = __builtin_bit_cast(sh8, dv);
        }

        // broadcast rescale into accO layout
        float fb[4];
        #pragma unroll
        for (int r = 0; r < 4; ++r) fb[r] = __shfl(f, lg*4 + r);
        #pragma unroll
        for (int n = 0; n < 4; ++n)
            #pragma unroll
            for (int r = 0; r < 4; ++r) accO[n][r] *= fb[r];

        // PV
        #pragma unroll
        for (int n = 0; n < 4; ++n) {
            int dcol = n*16 + lr;
            sh8 v0 = Vs8[buf][dcol*8 + (lg       ^ (dcol & 7))];
            sh8 v1 = Vs8[buf][dcol*8 + ((4 + lg) ^ (dcol & 7))];
            accO[n] = mfma16(pa[1], v1, mfma16(pa[0], v0, accO[n]));
        }

        asm volatile("s_waitcnt lgkmcnt(0)" ::: "memory");
    }
    #undef ASTAGE
    #undef RMLOAD

    l_lane += __shfl_xor(l_lane, 16);
    l_lane += __shfl_xor(l_lane, 32);

    short* Op = (ks < 2) ? OpA : OpB;
    #pragma unroll
    for (int r = 0; r < 4; ++r) {
        size_t row = (size_t)((ks & 1)*MTOK + qrow0 + lg*4 + r);
        #pragma unroll
        for (int n = 0; n < 4; ++n)
            Op[row*512 + h*64 + n*16 + lr] = f2bf(accO[n][r]);
    }
    if (lg == 0) {
        size_t mrow = (size_t)(ks*MTOK + qrow0 + lr);
        ml[(mrow*NHEADS + h)*2 + 0] = m_i;
        ml[(mrow*NHEADS + h)*2 + 1] = l_lane;
    }
}

// ---------------- combine 4 KV-split partials -> bf16 O ----------------
__global__ __launch_bounds__(256) void attn_combine4(const short* __restrict__ OpA,
    const short* __restrict__ OpB, const float* __restrict__ ml,
    short* __restrict__ ob)
{
    int idx = blockIdx.x*256 + threadIdx.x;     // MTOK*128 threads
    int tok = idx >> 7, dd = (idx & 127) * 4;
    int h = dd >> 6;
    float m[4], l[4];
    #pragma unroll
    for (int s = 0; s < 4; ++s) {
        m[s] = ml[(((size_t)s*MTOK + tok)*NHEADS + h)*2 + 0];
        l[s] = ml[(((size_t)s*MTOK + tok)*NHEADS + h)*2 + 1];
    }
    float mm = fmaxf(fmaxf(m[0], m[1]), fmaxf(m[2], m[3]));
    float wsum = 0.f, a0 = 0.f, a1 = 0.f, a2 = 0.f, a3 = 0.f;
    #pragma unroll
    for (int s = 0; s < 4; ++s) {
        float wv = ex2(m[s] - mm);
        wsum += wv * l[s];
        const short* Op = (s < 2) ? OpA : OpB;
        short4 p = *reinterpret_cast<const short4*>(&Op[((size_t)((s&1)*MTOK) + tok)*512 + dd]);
        a0 += bf2f(p.x)*wv; a1 += bf2f(p.y)*wv;
        a2 += bf2f(p.z)*wv; a3 += bf2f(p.w)*wv;
    }
    float inv = 1.f / wsum;
    short4 o;
    o.x = f2bf(a0*inv); o.y = f2bf(a1*inv);
    o.z = f2bf(a2*inv); o.w = f2bf(a3*inv);
    *reinterpret_cast<short4*>(&ob[(size_t)tok*512 + dd]) = o;
}

// -------------------------------------------------------------------------------
extern "C" void kernel_launch(void* const* d_in, const int* in_sizes, int n_in,
                              void* d_out, int out_size, void* d_ws, size_t ws_size,
                              hipStream_t stream)
{
    const float* x      = (const float*)d_in[0];
    const float* coords = (const float*)d_in[1];
    const unsigned char* mask = (const unsigned char*)d_in[2];
    const float* ln1_g = (const float*)d_in[3];
    const float* ln1_b = (const float*)d_in[4];
    const float* w_qkv = (const float*)d_in[5];
    const float* b_qkv = (const float*)d_in[6];
    const float* w_edge= (const float*)d_in[7];
    const float* w_out = (const float*)d_in[8];
    const float* b_out = (const float*)d_in[9];
    const float* ln2_g = (const float*)d_in[10];
    const float* ln2_b = (const float*)d_in[11];
    const float* w1    = (const float*)d_in[12];
    const float* b1    = (const float*)d_in[13];
    const float* w2    = (const float*)d_in[14];
    const float* b2    = (const float*)d_in[15];
    float* out = (float*)d_out;

    char* W = (char*)d_ws;
    const size_t MB = 1024*1024;
    float* x1    = (float*)(W);                    // [0,4M) f32 (written by outproj)
    short* qk    = (short*)(W + 4*MB);             // [4M,8M)
    short* vtb   = (short*)(W + 8*MB);             // [8M,10M)
    short* woutT = (short*)(W + 10*MB);            // [10M,10.5M)
    short* xln   = (short*)(W + 10*MB + 512*1024); // [10.5M,12.5M)  (later y)
    short* wqkvT = (short*)(W + 12*MB + 512*1024); // [12.5M,14M)
    short* OpB   = (short*)(W + 10*MB + 512*1024); // [10.5M,14.5M) over dead xln/wqkvT
    short* OpA   = (short*)(W + 14*MB + 512*1024); // [14.5M,18.5M)
    short* rnP   = (short*)(W + 18*MB + 512*1024); // [18.5M,22.5M) bf16 blocked
    float* mlp   = (float*)(W + 22*MB + 512*1024); // [22.5M,23M) 4x2048x8x2 f32
    unsigned long long* mbP = (unsigned long long*)(W + 23*MB); // [23M,23.25M) blocked
    short* ob    = (short*)(W + 6*MB);             // [6M,8M)  (qk dead after attn)
    short* y     = xln;                            // [10.5M,12.5M) (OpB dead)
    short* w1T   = (short*)(W + 4*MB);             // [4M,6M)  (qk dead)
    short* w2T   = (short*)(W + 8*MB);             // [8M,10M) (vtb dead)
    short* hid   = (short*)(W + 14*MB + 512*1024); // [14.5M,22.5M) (OpA/rnP dead)

    // ---- phase 1 ----
    prep<<<dim3(2048,1,1), 256, 0, stream>>>(coords, mask, rnP, mbP);
    wconv2x<<<dim3(1024,1,1), 256, 0, stream>>>(w_qkv, wqkvT, 512, 1536, 768,
                                                w_out, woutT, 512, 512);
    ln_bf16<false><<<MTOK, 256, 0, stream>>>(x, ln1_g, ln1_b, xln, nullptr, nullptr);
    gemm64<0,true,false,1,true,8><<<dim3(512,1,1), 256, 0, stream>>>(
        xln, wqkvT, b_qkv, nullptr, qk, MTOK, 1024, 512, 16);
    gemm64<0,true,true,1,false,8><<<dim3(256,1,1), 256, 0, stream>>>(
        wqkvT + (size_t)1024*512, xln, b_qkv + 1024, nullptr, vtb, 512, MTOK, 512, 32);
    attn_reg<<<dim3(1024,1,1), 256, 0, stream>>>(qk, vtb, rnP, mbP, w_edge, OpA, OpB, mlp);
    attn_combine4<<<dim3(1024,1,1), 256, 0, stream>>>(OpA, OpB, mlp, ob);
    // x1 = ob @ w_out + b_out + x   (no split-K, no atomics)
    gemm64<1,false,false,1,false,8><<<dim3(256,1,1), 256, 0, stream>>>(
        ob, woutT, b_out, x, x1, MTOK, 512, 512, 8);
    // ---- phase 2 ----
    wconv2x<<<dim3(2048,1,1), 256, 0, stream>>>(w1, w1T, 512, 2048, 1024,
                                                w2, w2T, 2048, 512);
    ln_bf16<true><<<MTOK, 256, 0, stream>>>(x1, ln2_g, ln2_b, y, b2, out);
    gemm64<2,true,false,1,false,8><<<dim3(1024,1,1), 256, 0, stream>>>(
        y, w1T, b1, nullptr, hid, MTOK, 2048, 512, 32);
    // out += hid @ w2   (split-K=2 atomics)
    gemm64<3,false,false,2,false,16><<<dim3(256,1,2), 256, 0, stream>>>(
        hid, w2T, nullptr, nullptr, out, MTOK, 512, 2048, 8);
}

// Round 15
// 92.324 us; speedup vs baseline: 1.8100x; 1.0056x over previous
//
#include <hip/hip_runtime.h>
#include <hip/hip_bf16.h>
#include <math.h>

#define NHEADS 8
#define NTOK   1024
#define MTOK   2048

typedef __attribute__((ext_vector_type(8))) short  sh8;
typedef __attribute__((ext_vector_type(8))) __bf16 bf16x8;
typedef __attribute__((ext_vector_type(4))) float  f32x4;
typedef __attribute__((ext_vector_type(4))) unsigned int u32x4;

__device__ __forceinline__ short f2bf(float v) {
    return __builtin_bit_cast(short, __float2bfloat16(v));
}
__device__ __forceinline__ float bf2f(short v) {
    return __builtin_bit_cast(float, ((unsigned)(unsigned short)v) << 16);
}
__device__ __forceinline__ float ex2(float v) {
    return __builtin_amdgcn_exp2f(v);
}
__device__ __forceinline__ f32x4 mfma16(sh8 a, sh8 b, f32x4 c) {
    return __builtin_amdgcn_mfma_f32_16x16x32_bf16(
        __builtin_bit_cast(bf16x8, a), __builtin_bit_cast(bf16x8, b), c, 0, 0, 0);
}
__device__ __forceinline__ void aload16(void* lds, const void* g) {
    __builtin_amdgcn_global_load_lds(
        (const __attribute__((address_space(1))) unsigned int*)g,
        (__attribute__((address_space(3))) unsigned int*)lds, 16, 0, 0);
}

#define LOG2E 1.4426950408889634f

// ---------------- LayerNorm -> bf16 ----------------
__global__ __launch_bounds__(256) void ln_bf16(const float* __restrict__ x,
    const float* __restrict__ g, const float* __restrict__ bta, short* __restrict__ y)
{
    int row = blockIdx.x, t = threadIdx.x;
    const float* xr = x + (size_t)row * 512;
    float2 v = *reinterpret_cast<const float2*>(&xr[t*2]);
    float s = v.x + v.y, ss = v.x*v.x + v.y*v.y;
    #pragma unroll
    for (int m = 1; m < 64; m <<= 1) { s += __shfl_xor(s, m); ss += __shfl_xor(ss, m); }
    __shared__ float red[8];
    int wid = t >> 6, lane = t & 63;
    if (!lane) { red[wid] = s; red[4+wid] = ss; }
    __syncthreads();
    s = red[0]+red[1]+red[2]+red[3]; ss = red[4]+red[5]+red[6]+red[7];
    float mu = s*(1.f/512), var = ss*(1.f/512) - mu*mu, rs = rsqrtf(var + 1e-5f);
    float2 gg = *reinterpret_cast<const float2*>(&g[t*2]);
    float2 bb = *reinterpret_cast<const float2*>(&bta[t*2]);
    short2 o; o.x = f2bf((v.x-mu)*rs*gg.x + bb.x); o.y = f2bf((v.y-mu)*rs*gg.y + bb.y);
    *reinterpret_cast<short2*>(&y[(size_t)row*512 + t*2]) = o;
}

// ---------------- merged: two fp32 W[K][N] -> bf16 W^T[N][K] transposes --------
__global__ __launch_bounds__(256) void wconv2x(
    const float* __restrict__ W0, short* __restrict__ WT0, int K0, int N0, int nb0,
    const float* __restrict__ W1, short* __restrict__ WT1, int K1, int N1)
{
    const float* W; short* WT; int K, N, bid;
    if ((int)blockIdx.x < nb0) { W = W0; WT = WT0; K = K0; N = N0; bid = blockIdx.x; }
    else                       { W = W1; WT = WT1; K = K1; N = N1; bid = blockIdx.x - nb0; }
    int nbx = N >> 5;
    int bn = (bid % nbx) * 32, bk = (bid / nbx) * 32;
    __shared__ float t[32][33];
    int c = threadIdx.x & 31, r8 = threadIdx.x >> 5;
    #pragma unroll
    for (int i = 0; i < 4; ++i) {
        int r = r8 + i*8;
        t[r][c] = W[(size_t)(bk + r)*N + bn + c];
    }
    __syncthreads();
    #pragma unroll
    for (int i = 0; i < 4; ++i) {
        int r = r8 + i*8;
        WT[(size_t)(bn + r)*K + bk + c] = f2bf(t[c][r]);
    }
}

// ---------------- prep: blocked rn table + blocked mask bits -------------------
__global__ __launch_bounds__(256) void prep(const float* __restrict__ coords,
    const unsigned char* __restrict__ mask, short* __restrict__ rnP,
    unsigned long long* __restrict__ mbP)
{
    __shared__ float2 kc_s[64];
    __shared__ float2 qc_s[16];
    int bid = blockIdx.x;                // bqt*16 + jt
    int bqt = bid >> 4, jt = bid & 15;
    int b = bqt >> 6, qt = bqt & 63;
    int t = threadIdx.x, w = t >> 6, lane = t & 63;
    int lr = lane & 15, lg = lane >> 4;

    if (t < 64)            kc_s[t]      = *reinterpret_cast<const float2*>(&coords[(size_t)(b*1024 + jt*64 + t)*2]);
    else if (t < 80)       qc_s[t - 64] = *reinterpret_cast<const float2*>(&coords[(size_t)(b*1024 + qt*16 + (t - 64))*2]);
    __syncthreads();

    float2 qc = qc_s[lr];
    short4 o;
    short* op = &o.x;
    #pragma unroll
    for (int r = 0; r < 4; ++r) {
        float2 kc = kc_s[w*16 + lg*4 + r];
        float dx = qc.x - kc.x, dy = qc.y - kc.y;
        op[r] = f2bf(sqrtf(dx*dx + dy*dy));
    }
    *reinterpret_cast<short4*>(&rnP[(size_t)((bid*4 + w)*256) + lane*4]) = o;

    #pragma unroll
    for (int i = 0; i < 4; ++i) {
        int q = w*4 + i;
        unsigned char v = mask[(size_t)(b*1024 + qt*16 + q)*NTOK + jt*64 + lane];
        unsigned long long bits = __ballot(v != 0);
        if (!lane) mbP[(size_t)bid*16 + q] = bits;
    }
}

// ---------------- bf16 MFMA GEMM, 64x64 tile, BK=64, 3-stage counted-vmcnt ----
// EPI: 0 bias; 1 bias+res (f32 out); 2 bias+gelu
template<int EPI, bool OUTBF, bool BIAS_ROW, bool QSC, int NT>
__global__ __launch_bounds__(256) void gemm64(
    const short* __restrict__ A, const short* __restrict__ BT,
    const float* __restrict__ bias, const float* __restrict__ res,
    void* __restrict__ Cout, int M, int N, int K, int nbx)
{
    __shared__ sh8 As8[3][512];
    __shared__ sh8 Bs8[3][512];
    int tid = threadIdx.x;
    int w = tid >> 6, lane = tid & 63, lr = lane & 15, lg = lane >> 4;
    int wr = w >> 1, wc = w & 1;
    int cpx = gridDim.x >> 3;
    int swz = (blockIdx.x & 7)*cpx + (blockIdx.x >> 3);
    int bx = swz % nbx, by = swz / nbx;
    int bm0 = by*64, bn0 = bx*64;

    f32x4 zero = {0.f,0.f,0.f,0.f};
    f32x4 acc[2][2];
    #pragma unroll
    for (int m = 0; m < 2; ++m)
        #pragma unroll
        for (int n = 0; n < 2; ++n) acc[m][n] = zero;

    #define STAGE(buf, k0) { \
        _Pragma("unroll") \
        for (int it = 0; it < 2; ++it) { \
            int s = tid + it*256; \
            int r = s >> 3, g = s & 7; \
            int ksw = (k0) + ((g ^ (r & 7)) << 3); \
            aload16(&As8[buf][s], A  + (size_t)(bm0 + r)*K + ksw); \
            aload16(&Bs8[buf][s], BT + (size_t)(bn0 + r)*K + ksw); \
        } }

    STAGE(0, 0)
    if (NT > 1) STAGE(1, 64)

    #pragma unroll
    for (int t = 0; t < NT; ++t) {
        if (t + 1 < NT) asm volatile("s_waitcnt vmcnt(4)" ::: "memory");
        else            asm volatile("s_waitcnt vmcnt(0)" ::: "memory");
        __builtin_amdgcn_s_barrier();
        __builtin_amdgcn_sched_barrier(0);
        int buf = t % 3;
        sh8 af[2][2], bfv[2][2];
        #pragma unroll
        for (int m = 0; m < 2; ++m) {
            int R = wr*32 + m*16 + lr;
            #pragma unroll
            for (int s = 0; s < 2; ++s) af[m][s] = As8[buf][R*8 + ((s*4+lg) ^ (R & 7))];
        }
        #pragma unroll
        for (int n = 0; n < 2; ++n) {
            int R = wc*32 + n*16 + lr;
            #pragma unroll
            for (int s = 0; s < 2; ++s) bfv[n][s] = Bs8[buf][R*8 + ((s*4+lg) ^ (R & 7))];
        }
        if (t + 2 < NT) STAGE((t+2)%3, (t+2)*64)
        #pragma unroll
        for (int m = 0; m < 2; ++m)
            #pragma unroll
            for (int n = 0; n < 2; ++n)
                #pragma unroll
                for (int s = 0; s < 2; ++s)
                    acc[m][n] = mfma16(af[m][s], bfv[n][s], acc[m][n]);
        asm volatile("s_waitcnt lgkmcnt(0)" ::: "memory");
    }
    #undef STAGE

    #pragma unroll
    for (int m = 0; m < 2; ++m) {
        #pragma unroll
        for (int n = 0; n < 2; ++n) {
            #pragma unroll
            for (int r = 0; r < 4; ++r) {
                int row = bm0 + wr*32 + m*16 + lg*4 + r;
                int col = bn0 + wc*32 + n*16 + lr;
                float v = acc[m][n][r] + (BIAS_ROW ? bias[row] : bias[col]);
                if (QSC && col < 512) v *= (0.125f * LOG2E);
                if (EPI == 1) v += res[(size_t)row*N + col];
                if (EPI == 2) v = 0.5f * v * (1.0f + erff(v * 0.70710678f));
                if (OUTBF) ((short*)Cout)[(size_t)row*N + col] = f2bf(v);
                else       ((float*)Cout)[(size_t)row*N + col] = v;
            }
        }
    }
}

// ---------------- bf16 MFMA GEMM, 64x32 tile (2 blocks/CU for small-N) --------
// 4 waves, each computes 16 rows x 32 cols. 3 loads/thread/stage -> vmcnt(3).
template<int EPI, bool OUTBF, bool BIAS_ROW, int NT>
__global__ __launch_bounds__(256) void gemm32n(
    const short* __restrict__ A, const short* __restrict__ BT,
    const float* __restrict__ bias, const float* __restrict__ res,
    void* __restrict__ Cout, int M, int N, int K, int nbx)
{
    __shared__ sh8 As8[3][512];
    __shared__ sh8 Bs8[3][256];
    int tid = threadIdx.x;
    int w = tid >> 6, lane = tid & 63, lr = lane & 15, lg = lane >> 4;
    int cpx = gridDim.x >> 3;
    int swz = (blockIdx.x & 7)*cpx + (blockIdx.x >> 3);
    int bx = swz % nbx, by = swz / nbx;
    int bm0 = by*64, bn0 = bx*32;

    f32x4 zero = {0.f,0.f,0.f,0.f};
    f32x4 acc[2];
    acc[0] = zero; acc[1] = zero;

    #define STAGE32(buf, k0) { \
        _Pragma("unroll") \
        for (int it = 0; it < 2; ++it) { \
            int s = tid + it*256; \
            int r = s >> 3, g = s & 7; \
            int ksw = (k0) + ((g ^ (r & 7)) << 3); \
            aload16(&As8[buf][s], A + (size_t)(bm0 + r)*K + ksw); \
        } \
        { int r = tid >> 3, g = tid & 7; \
          int ksw = (k0) + ((g ^ (r & 7)) << 3); \
          aload16(&Bs8[buf][tid], BT + (size_t)(bn0 + r)*K + ksw); } }

    STAGE32(0, 0)
    if (NT > 1) STAGE32(1, 64)

    #pragma unroll
    for (int t = 0; t < NT; ++t) {
        if (t + 1 < NT) asm volatile("s_waitcnt vmcnt(3)" ::: "memory");
        else            asm volatile("s_waitcnt vmcnt(0)" ::: "memory");
        __builtin_amdgcn_s_barrier();
        __builtin_amdgcn_sched_barrier(0);
        int buf = t % 3;
        sh8 af[2], bfv[2][2];
        int Ra = w*16 + lr;
        #pragma unroll
        for (int s = 0; s < 2; ++s) af[s] = As8[buf][Ra*8 + ((s*4+lg) ^ (Ra & 7))];
        #pragma unroll
        for (int n = 0; n < 2; ++n) {
            int R = n*16 + lr;
            #pragma unroll
            for (int s = 0; s < 2; ++s) bfv[n][s] = Bs8[buf][R*8 + ((s*4+lg) ^ (R & 7))];
        }
        if (t + 2 < NT) STAGE32((t+2)%3, (t+2)*64)
        #pragma unroll
        for (int n = 0; n < 2; ++n)
            #pragma unroll
            for (int s = 0; s < 2; ++s)
                acc[n] = mfma16(af[s], bfv[n][s], acc[n]);
        asm volatile("s_waitcnt lgkmcnt(0)" ::: "memory");
    }
    #undef STAGE32

    #pragma unroll
    for (int n = 0; n < 2; ++n) {
        #pragma unroll
        for (int r = 0; r < 4; ++r) {
            int row = bm0 + w*16 + lg*4 + r;
            int col = bn0 + n*16 + lr;
            float v = acc[n][r] + (BIAS_ROW ? bias[row] : bias[col]);
            if (EPI == 1) v += res[(size_t)row*N + col];
            if (EPI == 2) v = 0.5f * v * (1.0f + erff(v * 0.70710678f));
            if (OUTBF) ((short*)Cout)[(size_t)row*N + col] = f2bf(v);
            else       ((float*)Cout)[(size_t)row*N + col] = v;
        }
    }
}

// ---------------- LDS-staged MFMA flash attention, KV-split x4, swapped QK ----
__global__ __launch_bounds__(256) void attn_reg(
    const short* __restrict__ qk, const short* __restrict__ vt,
    const short* __restrict__ rnP, const unsigned long long* __restrict__ mbP,
    const float* __restrict__ w_edge, short* __restrict__ OpA,
    short* __restrict__ OpB, float* __restrict__ ml)
{
    __shared__ sh8 Ks8[2][512];
    __shared__ sh8 Vs8[2][512];

    int cpx = gridDim.x >> 3;
    int swz = (blockIdx.x & 7)*cpx + (blockIdx.x >> 3);
    int w = threadIdx.x >> 6, lane = threadIdx.x & 63;
    int lr = lane & 15, lg = lane >> 4;
    int qb = swz & 15;
    int h  = (swz >> 4) & 7;
    int b  = (swz >> 7) & 1;
    int ks = swz >> 8;

    const int q0 = qb*64 + w*16;
    const int qrow0 = b*NTOK + q0;
    const int jt0 = ks*4;
    const int bqt = b*64 + qb*4 + w;

    sh8 qf[2];
    #pragma unroll
    for (int s = 0; s < 2; ++s)
        qf[s] = *reinterpret_cast<const sh8*>(qk + (size_t)(qrow0 + lr)*1024 + h*64 + s*32 + lg*8);

    float we2l = w_edge[2*NHEADS + h] * LOG2E;

    float m_i = -1e30f, l_lane = 0.f;
    f32x4 zero = {0.f,0.f,0.f,0.f};
    f32x4 accO[4];
    #pragma unroll
    for (int n = 0; n < 4; ++n) accO[n] = zero;

    const short* kbase = qk + 512 + h*64;
    const short* vbase = vt + (size_t)h*64*2048 + b*NTOK;
    int sr = threadIdx.x >> 3, sg = threadIdx.x & 7;
    int sx = (sg ^ (sr & 7)) << 3;

    #define ASTAGE(bf, jt) { \
        aload16(&Ks8[bf][threadIdx.x],       kbase + (size_t)(b*NTOK + (jt)*64 + sr)*1024 + sx); \
        aload16(&Ks8[bf][threadIdx.x + 256], kbase + (size_t)(b*NTOK + (jt)*64 + sr + 32)*1024 + sx); \
        aload16(&Vs8[bf][threadIdx.x],       vbase + (size_t)sr*2048 + (jt)*64 + sx); \
        aload16(&Vs8[bf][threadIdx.x + 256], vbase + (size_t)(sr + 32)*2048 + (jt)*64 + sx); \
    }

    short4 rn_reg[2][4];
    unsigned long long mr_reg[2];
    #define RMLOAD(bf, jt) { \
        _Pragma("unroll") \
        for (int n = 0; n < 4; ++n) \
            rn_reg[bf][n] = *reinterpret_cast<const short4*>( \
                &rnP[(size_t)(((bqt*16 + (jt))*4 + n)*256) + lane*4]); \
        mr_reg[bf] = mbP[(size_t)(bqt*16 + (jt))*16 + lr]; \
    }

    ASTAGE(0, jt0)
    RMLOAD(0, jt0)

    #pragma unroll
    for (int t = 0; t < 4; ++t) {
        if (t == 0) asm volatile("s_waitcnt vmcnt(0)" ::: "memory");
        else        asm volatile("s_waitcnt vmcnt(5)" ::: "memory");
        __builtin_amdgcn_s_barrier();
        __builtin_amdgcn_sched_barrier(0);
        int buf = t & 1;

        if (t + 1 < 4) {
            ASTAGE(buf ^ 1, jt0 + t + 1)
            RMLOAD(buf ^ 1, jt0 + t + 1)
        }

        // S^T = K Q^T
        f32x4 Sv[4];
        #pragma unroll
        for (int n = 0; n < 4; ++n) {
            int kcol = n*16 + lr;
            sh8 k0v = Ks8[buf][kcol*8 + (lg       ^ (kcol & 7))];
            sh8 k1v = Ks8[buf][kcol*8 + ((4 + lg) ^ (kcol & 7))];
            Sv[n] = mfma16(k1v, qf[1], mfma16(k0v, qf[0], zero));
        }

        // radial bias (log2 domain)
        #pragma unroll
        for (int n = 0; n < 4; ++n) {
            short4 rn4 = rn_reg[buf][n];
            Sv[n][0] = fmaf(bf2f(rn4.x), we2l, Sv[n][0]);
            Sv[n][1] = fmaf(bf2f(rn4.y), we2l, Sv[n][1]);
            Sv[n][2] = fmaf(bf2f(rn4.z), we2l, Sv[n][2]);
            Sv[n][3] = fmaf(bf2f(rn4.w), we2l, Sv[n][3]);
        }

        // lane-local max + 2-shfl reduce
        float mx = Sv[0][0];
        #pragma unroll
        for (int n = 0; n < 4; ++n)
            #pragma unroll
            for (int r = 0; r < 4; ++r) mx = fmaxf(mx, Sv[n][r]);
        mx = fmaxf(mx, __shfl_xor(mx, 16));
        mx = fmaxf(mx, __shfl_xor(mx, 32));

        // defer-rescale (THR=8 log2 units): skip O/l rescale when max growth small
        if (!__all(mx <= m_i + 8.0f)) {
            float mnew = fmaxf(m_i, mx);
            float f = ex2(m_i - mnew);
            m_i = mnew;
            l_lane *= f;
            float fb[4];
            #pragma unroll
            for (int r = 0; r < 4; ++r) fb[r] = __shfl(f, lg*4 + r);
            #pragma unroll
            for (int n = 0; n < 4; ++n)
                #pragma unroll
                for (int r = 0; r < 4; ++r) accO[n][r] *= fb[r];
        }

        // exp, post-exp mask-zero, lane-partial sum, packed bf16 via cvt_pk
        unsigned long long mr = mr_reg[buf];
        float ps = 0.f;
        unsigned pk[8];
        #pragma unroll
        for (int n = 0; n < 4; ++n) {
            float p_[4];
            #pragma unroll
            for (int r = 0; r < 4; ++r) {
                float p = ex2(Sv[n][r] - m_i);
                p = ((mr >> (n*16 + lg*4 + r)) & 1ull) ? 0.f : p;
                ps += p;
                p_[r] = p;
            }
            asm("v_cvt_pk_bf16_f32 %0, %1, %2" : "=v"(pk[2*n])   : "v"(p_[0]), "v"(p_[1]));
            asm("v_cvt_pk_bf16_f32 %0, %1, %2" : "=v"(pk[2*n+1]) : "v"(p_[2]), "v"(p_[3]));
        }
        l_lane += ps;

        // PA fragments via shfl
        int src0 = lr + ((lg & 1) << 5);
        int src1 = src0 + 16;
        sh8 pa[2];
        #pragma unroll
        for (int s = 0; s < 2; ++s) {
            int ns = 2*s + (lg >> 1);
            u32x4 dv;
            dv.x = (unsigned)__shfl((int)pk[2*ns],   src0);
            dv.y = (unsigned)__shfl((int)pk[2*ns+1], src0);
            dv.z = (unsigned)__shfl((int)pk[2*ns],   src1);
            dv.w = (unsigned)__shfl((int)pk[2*ns+1], src1);
            pa[s] = __builtin_bit_cast(sh8, dv);
        }

        // PV
        #pragma unroll
        for (int n = 0; n < 4; ++n) {
            int dcol = n*16 + lr;
            sh8 v0 = Vs8[buf][dcol*8 + (lg       ^ (dcol & 7))];
            sh8 v1 = Vs8[buf][dcol*8 + ((4 + lg) ^ (dcol & 7))];
            accO[n] = mfma16(pa[1], v1, mfma16(pa[0], v0, accO[n]));
        }

        asm volatile("s_waitcnt lgkmcnt(0)" ::: "memory");
    }
    #undef ASTAGE
    #undef RMLOAD

    l_lane += __shfl_xor(l_lane, 16);
    l_lane += __shfl_xor(l_lane, 32);

    short* Op = (ks < 2) ? OpA : OpB;
    #pragma unroll
    for (int r = 0; r < 4; ++r) {
        size_t row = (size_t)((ks & 1)*MTOK + qrow0 + lg*4 + r);
        #pragma unroll
        for (int n = 0; n < 4; ++n)
            Op[row*512 + h*64 + n*16 + lr] = f2bf(accO[n][r]);
    }
    if (lg == 0) {
        size_t mrow = (size_t)(ks*MTOK + qrow0 + lr);
        ml[(mrow*NHEADS + h)*2 + 0] = m_i;
        ml[(mrow*NHEADS + h)*2 + 1] = l_lane;
    }
}

// ---------------- combine 4 KV-split partials -> bf16 O ----------------
__global__ __launch_bounds__(256) void attn_combine4(const short* __restrict__ OpA,
    const short* __restrict__ OpB, const float* __restrict__ ml,
    short* __restrict__ ob)
{
    int idx = blockIdx.x*256 + threadIdx.x;
    int tok = idx >> 7, dd = (idx & 127) * 4;
    int h = dd >> 6;
    float m[4], l[4];
    #pragma unroll
    for (int s = 0; s < 4; ++s) {
        m[s] = ml[(((size_t)s*MTOK + tok)*NHEADS + h)*2 + 0];
        l[s] = ml[(((size_t)s*MTOK + tok)*NHEADS + h)*2 + 1];
    }
    float mm = fmaxf(fmaxf(m[0], m[1]), fmaxf(m[2], m[3]));
    float wsum = 0.f, a0 = 0.f, a1 = 0.f, a2 = 0.f, a3 = 0.f;
    #pragma unroll
    for (int s = 0; s < 4; ++s) {
        float wv = ex2(m[s] - mm);
        wsum += wv * l[s];
        const short* Op = (s < 2) ? OpA : OpB;
        short4 p = *reinterpret_cast<const short4*>(&Op[((size_t)((s&1)*MTOK) + tok)*512 + dd]);
        a0 += bf2f(p.x)*wv; a1 += bf2f(p.y)*wv;
        a2 += bf2f(p.z)*wv; a3 += bf2f(p.w)*wv;
    }
    float inv = 1.f / wsum;
    short4 o;
    o.x = f2bf(a0*inv); o.y = f2bf(a1*inv);
    o.z = f2bf(a2*inv); o.w = f2bf(a3*inv);
    *reinterpret_cast<short4*>(&ob[(size_t)tok*512 + dd]) = o;
}

// -------------------------------------------------------------------------------
extern "C" void kernel_launch(void* const* d_in, const int* in_sizes, int n_in,
                              void* d_out, int out_size, void* d_ws, size_t ws_size,
                              hipStream_t stream)
{
    const float* x      = (const float*)d_in[0];
    const float* coords = (const float*)d_in[1];
    const unsigned char* mask = (const unsigned char*)d_in[2];
    const float* ln1_g = (const float*)d_in[3];
    const float* ln1_b = (const float*)d_in[4];
    const float* w_qkv = (const float*)d_in[5];
    const float* b_qkv = (const float*)d_in[6];
    const float* w_edge= (const float*)d_in[7];
    const float* w_out = (const float*)d_in[8];
    const float* b_out = (const float*)d_in[9];
    const float* ln2_g = (const float*)d_in[10];
    const float* ln2_b = (const float*)d_in[11];
    const float* w1    = (const float*)d_in[12];
    const float* b1    = (const float*)d_in[13];
    const float* w2    = (const float*)d_in[14];
    const float* b2    = (const float*)d_in[15];
    float* out = (float*)d_out;

    char* W = (char*)d_ws;
    const size_t MB = 1024*1024;
    float* x1    = (float*)(W);                    // [0,4M)
    short* qk    = (short*)(W + 4*MB);             // [4M,8M)
    short* vtb   = (short*)(W + 8*MB);             // [8M,10M)
    short* woutT = (short*)(W + 10*MB);            // [10M,10.5M)
    short* xln   = (short*)(W + 10*MB + 512*1024); // [10.5M,12.5M)  (later y)
    short* wqkvT = (short*)(W + 12*MB + 512*1024); // [12.5M,14M)
    short* OpB   = (short*)(W + 10*MB + 512*1024); // [10.5M,14.5M)
    short* OpA   = (short*)(W + 14*MB + 512*1024); // [14.5M,18.5M)
    short* rnP   = (short*)(W + 18*MB + 512*1024); // [18.5M,22.5M)
    float* mlp   = (float*)(W + 22*MB + 512*1024); // [22.5M,23M)
    unsigned long long* mbP = (unsigned long long*)(W + 23*MB); // [23M,23.25M)
    short* ob    = (short*)(W + 6*MB);             // [6M,8M)
    short* y     = xln;
    short* w1T   = (short*)(W + 4*MB);             // [4M,6M)
    short* w2T   = (short*)(W + 8*MB);             // [8M,10M)
    short* hid   = (short*)(W + 14*MB + 512*1024); // [14.5M,22.5M)

    // ---- phase 1 ----
    prep<<<dim3(2048,1,1), 256, 0, stream>>>(coords, mask, rnP, mbP);
    wconv2x<<<dim3(1024,1,1), 256, 0, stream>>>(w_qkv, wqkvT, 512, 1536, 768,
                                                w_out, woutT, 512, 512);
    ln_bf16<<<MTOK, 256, 0, stream>>>(x, ln1_g, ln1_b, xln);
    gemm64<0,true,false,true,8><<<dim3(512,1,1), 256, 0, stream>>>(
        xln, wqkvT, b_qkv, nullptr, qk, MTOK, 1024, 512, 16);
    // vt = Wv^T @ xln^T  (64x32 tiles, 512 blocks)
    gemm32n<0,true,true,8><<<dim3(512,1,1), 256, 0, stream>>>(
        wqkvT + (size_t)1024*512, xln, b_qkv + 1024, nullptr, vtb, 512, MTOK, 512, 64);
    attn_reg<<<dim3(1024,1,1), 256, 0, stream>>>(qk, vtb, rnP, mbP, w_edge, OpA, OpB, mlp);
    attn_combine4<<<dim3(1024,1,1), 256, 0, stream>>>(OpA, OpB, mlp, ob);
    // x1 = ob @ w_out + b_out + x  (64x32 tiles, 512 blocks)
    gemm32n<1,false,false,8><<<dim3(512,1,1), 256, 0, stream>>>(
        ob, woutT, b_out, x, x1, MTOK, 512, 512, 16);
    // ---- phase 2 ----
    wconv2x<<<dim3(2048,1,1), 256, 0, stream>>>(w1, w1T, 512, 2048, 1024,
                                                w2, w2T, 2048, 512);
    ln_bf16<<<MTOK, 256, 0, stream>>>(x1, ln2_g, ln2_b, y);
    gemm64<2,true,false,false,8><<<dim3(1024,1,1), 256, 0, stream>>>(
        y, w1T, b1, nullptr, hid, MTOK, 2048, 512, 32);
    // out = hid @ w2 + b2 + x1  (64x32 tiles, 512 blocks, NT=32, no atomics)
    gemm32n<1,false,false,32><<<dim3(512,1,1), 256, 0, stream>>>(
        hid, w2T, b2, x1, out, MTOK, 512, 2048, 16);
}

// Round 16
// 85.407 us; speedup vs baseline: 1.9566x; 1.0810x over previous
//
#include <hip/hip_runtime.h>
#include <hip/hip_bf16.h>
#include <math.h>

#define NHEADS 8
#define NTOK   1024
#define MTOK   2048

typedef __attribute__((ext_vector_type(8))) short  sh8;
typedef __attribute__((ext_vector_type(8))) __bf16 bf16x8;
typedef __attribute__((ext_vector_type(4))) float  f32x4;
typedef __attribute__((ext_vector_type(4))) unsigned int u32x4;

__device__ __forceinline__ short f2bf(float v) {
    return __builtin_bit_cast(short, __float2bfloat16(v));
}
__device__ __forceinline__ float bf2f(short v) {
    return __builtin_bit_cast(float, ((unsigned)(unsigned short)v) << 16);
}
__device__ __forceinline__ float ex2(float v) {
    return __builtin_amdgcn_exp2f(v);
}
__device__ __forceinline__ f32x4 mfma16(sh8 a, sh8 b, f32x4 c) {
    return __builtin_amdgcn_mfma_f32_16x16x32_bf16(
        __builtin_bit_cast(bf16x8, a), __builtin_bit_cast(bf16x8, b), c, 0, 0, 0);
}
__device__ __forceinline__ void aload16(void* lds, const void* g) {
    __builtin_amdgcn_global_load_lds(
        (const __attribute__((address_space(1))) unsigned int*)g,
        (__attribute__((address_space(3))) unsigned int*)lds, 16, 0, 0);
}

#define LOG2E 1.4426950408889634f

// ---------------- LayerNorm -> bf16 ----------------
__global__ __launch_bounds__(256) void ln_bf16(const float* __restrict__ x,
    const float* __restrict__ g, const float* __restrict__ bta, short* __restrict__ y)
{
    int row = blockIdx.x, t = threadIdx.x;
    const float* xr = x + (size_t)row * 512;
    float2 v = *reinterpret_cast<const float2*>(&xr[t*2]);
    float s = v.x + v.y, ss = v.x*v.x + v.y*v.y;
    #pragma unroll
    for (int m = 1; m < 64; m <<= 1) { s += __shfl_xor(s, m); ss += __shfl_xor(ss, m); }
    __shared__ float red[8];
    int wid = t >> 6, lane = t & 63;
    if (!lane) { red[wid] = s; red[4+wid] = ss; }
    __syncthreads();
    s = red[0]+red[1]+red[2]+red[3]; ss = red[4]+red[5]+red[6]+red[7];
    float mu = s*(1.f/512), var = ss*(1.f/512) - mu*mu, rs = rsqrtf(var + 1e-5f);
    float2 gg = *reinterpret_cast<const float2*>(&g[t*2]);
    float2 bb = *reinterpret_cast<const float2*>(&bta[t*2]);
    short2 o; o.x = f2bf((v.x-mu)*rs*gg.x + bb.x); o.y = f2bf((v.y-mu)*rs*gg.y + bb.y);
    *reinterpret_cast<short2*>(&y[(size_t)row*512 + t*2]) = o;
}

// ---------------- merged: two fp32 W[K][N] -> bf16 W^T[N][K] transposes --------
__global__ __launch_bounds__(256) void wconv2x(
    const float* __restrict__ W0, short* __restrict__ WT0, int K0, int N0, int nb0,
    const float* __restrict__ W1, short* __restrict__ WT1, int K1, int N1)
{
    const float* W; short* WT; int K, N, bid;
    if ((int)blockIdx.x < nb0) { W = W0; WT = WT0; K = K0; N = N0; bid = blockIdx.x; }
    else                       { W = W1; WT = WT1; K = K1; N = N1; bid = blockIdx.x - nb0; }
    int nbx = N >> 5;
    int bn = (bid % nbx) * 32, bk = (bid / nbx) * 32;
    __shared__ float t[32][33];
    int c = threadIdx.x & 31, r8 = threadIdx.x >> 5;
    #pragma unroll
    for (int i = 0; i < 4; ++i) {
        int r = r8 + i*8;
        t[r][c] = W[(size_t)(bk + r)*N + bn + c];
    }
    __syncthreads();
    #pragma unroll
    for (int i = 0; i < 4; ++i) {
        int r = r8 + i*8;
        WT[(size_t)(bn + r)*K + bk + c] = f2bf(t[c][r]);
    }
}

// ---------------- prep: blocked rn table + blocked mask bits -------------------
__global__ __launch_bounds__(256) void prep(const float* __restrict__ coords,
    const unsigned char* __restrict__ mask, short* __restrict__ rnP,
    unsigned long long* __restrict__ mbP)
{
    __shared__ float2 kc_s[64];
    __shared__ float2 qc_s[16];
    int bid = blockIdx.x;                // bqt*16 + jt
    int bqt = bid >> 4, jt = bid & 15;
    int b = bqt >> 6, qt = bqt & 63;
    int t = threadIdx.x, w = t >> 6, lane = t & 63;
    int lr = lane & 15, lg = lane >> 4;

    if (t < 64)            kc_s[t]      = *reinterpret_cast<const float2*>(&coords[(size_t)(b*1024 + jt*64 + t)*2]);
    else if (t < 80)       qc_s[t - 64] = *reinterpret_cast<const float2*>(&coords[(size_t)(b*1024 + qt*16 + (t - 64))*2]);
    __syncthreads();

    float2 qc = qc_s[lr];
    short4 o;
    short* op = &o.x;
    #pragma unroll
    for (int r = 0; r < 4; ++r) {
        float2 kc = kc_s[w*16 + lg*4 + r];
        float dx = qc.x - kc.x, dy = qc.y - kc.y;
        op[r] = f2bf(sqrtf(dx*dx + dy*dy));
    }
    *reinterpret_cast<short4*>(&rnP[(size_t)((bid*4 + w)*256) + lane*4]) = o;

    #pragma unroll
    for (int i = 0; i < 4; ++i) {
        int q = w*4 + i;
        unsigned char v = mask[(size_t)(b*1024 + qt*16 + q)*NTOK + jt*64 + lane];
        unsigned long long bits = __ballot(v != 0);
        if (!lane) mbP[(size_t)bid*16 + q] = bits;
    }
}

// ---------------- bf16 MFMA GEMM, 64x64 tile, BK=64, 3-stage counted-vmcnt ----
// EPI: 0 bias; 1 bias+res (f32 out); 2 bias+gelu
// VTOUT: cols >= 1024 are v-dims -> LDS-transpose epilogue into vtx[vd][tok]
template<int EPI, bool OUTBF, bool BIAS_ROW, bool QSC, int NT, bool VTOUT>
__global__ __launch_bounds__(256) void gemm64(
    const short* __restrict__ A, const short* __restrict__ BT,
    const float* __restrict__ bias, const float* __restrict__ res,
    void* __restrict__ Cout, short* __restrict__ vtx,
    int M, int N, int K, int nbx, int ldc)
{
    __shared__ sh8 As8[3][512];
    __shared__ sh8 Bs8[3][512];
    int tid = threadIdx.x;
    int w = tid >> 6, lane = tid & 63, lr = lane & 15, lg = lane >> 4;
    int wr = w >> 1, wc = w & 1;
    int cpx = gridDim.x >> 3;
    int swz = (blockIdx.x & 7)*cpx + (blockIdx.x >> 3);
    int bx = swz % nbx, by = swz / nbx;
    int bm0 = by*64, bn0 = bx*64;

    f32x4 zero = {0.f,0.f,0.f,0.f};
    f32x4 acc[2][2];
    #pragma unroll
    for (int m = 0; m < 2; ++m)
        #pragma unroll
        for (int n = 0; n < 2; ++n) acc[m][n] = zero;

    #define STAGE(buf, k0) { \
        _Pragma("unroll") \
        for (int it = 0; it < 2; ++it) { \
            int s = tid + it*256; \
            int r = s >> 3, g = s & 7; \
            int ksw = (k0) + ((g ^ (r & 7)) << 3); \
            aload16(&As8[buf][s], A  + (size_t)(bm0 + r)*K + ksw); \
            aload16(&Bs8[buf][s], BT + (size_t)(bn0 + r)*K + ksw); \
        } }

    STAGE(0, 0)
    if (NT > 1) STAGE(1, 64)

    #pragma unroll
    for (int t = 0; t < NT; ++t) {
        if (t + 1 < NT) asm volatile("s_waitcnt vmcnt(4)" ::: "memory");
        else            asm volatile("s_waitcnt vmcnt(0)" ::: "memory");
        __builtin_amdgcn_s_barrier();
        __builtin_amdgcn_sched_barrier(0);
        int buf = t % 3;
        sh8 af[2][2], bfv[2][2];
        #pragma unroll
        for (int m = 0; m < 2; ++m) {
            int R = wr*32 + m*16 + lr;
            #pragma unroll
            for (int s = 0; s < 2; ++s) af[m][s] = As8[buf][R*8 + ((s*4+lg) ^ (R & 7))];
        }
        #pragma unroll
        for (int n = 0; n < 2; ++n) {
            int R = wc*32 + n*16 + lr;
            #pragma unroll
            for (int s = 0; s < 2; ++s) bfv[n][s] = Bs8[buf][R*8 + ((s*4+lg) ^ (R & 7))];
        }
        if (t + 2 < NT) STAGE((t+2)%3, (t+2)*64)
        #pragma unroll
        for (int m = 0; m < 2; ++m)
            #pragma unroll
            for (int n = 0; n < 2; ++n)
                #pragma unroll
                for (int s = 0; s < 2; ++s)
                    acc[m][n] = mfma16(af[m][s], bfv[n][s], acc[m][n]);
        asm volatile("s_waitcnt lgkmcnt(0)" ::: "memory");
    }
    #undef STAGE

    if (VTOUT && bn0 >= 1024) {
        // v-columns: transpose via LDS, store vtx[vd][tok] coalesced
        __syncthreads();
        short* tb = (short*)&As8[0][0];   // 64 x 68 shorts
        #pragma unroll
        for (int m = 0; m < 2; ++m)
            #pragma unroll
            for (int n = 0; n < 2; ++n)
                #pragma unroll
                for (int r = 0; r < 4; ++r) {
                    int row = wr*32 + m*16 + lg*4 + r;       // tok-local
                    int col = wc*32 + n*16 + lr;             // vd-local
                    float v = acc[m][n][r] + bias[bn0 + col];
                    tb[col*68 + row] = f2bf(v);
                }
        __syncthreads();
        int vd = tid >> 2, t0 = (tid & 3) << 4;
        #pragma unroll
        for (int i = 0; i < 4; ++i) {
            short4 s4 = *reinterpret_cast<short4*>(&tb[vd*68 + t0 + i*4]);
            *reinterpret_cast<short4*>(&vtx[(size_t)(bn0 - 1024 + vd)*2048 + bm0 + t0 + i*4]) = s4;
        }
        return;
    }

    #pragma unroll
    for (int m = 0; m < 2; ++m) {
        #pragma unroll
        for (int n = 0; n < 2; ++n) {
            #pragma unroll
            for (int r = 0; r < 4; ++r) {
                int row = bm0 + wr*32 + m*16 + lg*4 + r;
                int col = bn0 + wc*32 + n*16 + lr;
                float v = acc[m][n][r] + (BIAS_ROW ? bias[row] : bias[col]);
                if (QSC && col < 512) v *= (0.125f * LOG2E);
                if (EPI == 1) v += res[(size_t)row*ldc + col];
                if (EPI == 2) v = 0.5f * v * (1.0f + erff(v * 0.70710678f));
                if (OUTBF) ((short*)Cout)[(size_t)row*ldc + col] = f2bf(v);
                else       ((float*)Cout)[(size_t)row*ldc + col] = v;
            }
        }
    }
}

// ---------------- bf16 MFMA GEMM, 64x32 tile ----------------
template<int EPI, bool OUTBF, bool BIAS_ROW, int NT>
__global__ __launch_bounds__(256) void gemm32n(
    const short* __restrict__ A, const short* __restrict__ BT,
    const float* __restrict__ bias, const float* __restrict__ res,
    void* __restrict__ Cout, int M, int N, int K, int nbx)
{
    __shared__ sh8 As8[3][512];
    __shared__ sh8 Bs8[3][256];
    int tid = threadIdx.x;
    int w = tid >> 6, lane = tid & 63, lr = lane & 15, lg = lane >> 4;
    int cpx = gridDim.x >> 3;
    int swz = (blockIdx.x & 7)*cpx + (blockIdx.x >> 3);
    int bx = swz % nbx, by = swz / nbx;
    int bm0 = by*64, bn0 = bx*32;

    f32x4 zero = {0.f,0.f,0.f,0.f};
    f32x4 acc[2];
    acc[0] = zero; acc[1] = zero;

    #define STAGE32(buf, k0) { \
        _Pragma("unroll") \
        for (int it = 0; it < 2; ++it) { \
            int s = tid + it*256; \
            int r = s >> 3, g = s & 7; \
            int ksw = (k0) + ((g ^ (r & 7)) << 3); \
            aload16(&As8[buf][s], A + (size_t)(bm0 + r)*K + ksw); \
        } \
        { int r = tid >> 3, g = tid & 7; \
          int ksw = (k0) + ((g ^ (r & 7)) << 3); \
          aload16(&Bs8[buf][tid], BT + (size_t)(bn0 + r)*K + ksw); } }

    STAGE32(0, 0)
    if (NT > 1) STAGE32(1, 64)

    #pragma unroll
    for (int t = 0; t < NT; ++t) {
        if (t + 1 < NT) asm volatile("s_waitcnt vmcnt(3)" ::: "memory");
        else            asm volatile("s_waitcnt vmcnt(0)" ::: "memory");
        __builtin_amdgcn_s_barrier();
        __builtin_amdgcn_sched_barrier(0);
        int buf = t % 3;
        sh8 af[2], bfv[2][2];
        int Ra = w*16 + lr;
        #pragma unroll
        for (int s = 0; s < 2; ++s) af[s] = As8[buf][Ra*8 + ((s*4+lg) ^ (Ra & 7))];
        #pragma unroll
        for (int n = 0; n < 2; ++n) {
            int R = n*16 + lr;
            #pragma unroll
            for (int s = 0; s < 2; ++s) bfv[n][s] = Bs8[buf][R*8 + ((s*4+lg) ^ (R & 7))];
        }
        if (t + 2 < NT) STAGE32((t+2)%3, (t+2)*64)
        #pragma unroll
        for (int n = 0; n < 2; ++n)
            #pragma unroll
            for (int s = 0; s < 2; ++s)
                acc[n] = mfma16(af[s], bfv[n][s], acc[n]);
        asm volatile("s_waitcnt lgkmcnt(0)" ::: "memory");
    }
    #undef STAGE32

    #pragma unroll
    for (int n = 0; n < 2; ++n) {
        #pragma unroll
        for (int r = 0; r < 4; ++r) {
            int row = bm0 + w*16 + lg*4 + r;
            int col = bn0 + n*16 + lr;
            float v = acc[n][r] + (BIAS_ROW ? bias[row] : bias[col]);
            if (EPI == 1) v += res[(size_t)row*N + col];
            if (EPI == 2) v = 0.5f * v * (1.0f + erff(v * 0.70710678f));
            if (OUTBF) ((short*)Cout)[(size_t)row*N + col] = f2bf(v);
            else       ((float*)Cout)[(size_t)row*N + col] = v;
        }
    }
}

// ---------------- LDS-staged MFMA flash attention: 8 waves share K/V staging --
// 512 blocks (qb8 x h8 x b2 x ks4) x 512 threads. 2-buffer, vmcnt(5) counted.
__global__ __launch_bounds__(512) void attn_reg(
    const short* __restrict__ qk, const short* __restrict__ vt,
    const short* __restrict__ rnP, const unsigned long long* __restrict__ mbP,
    const float* __restrict__ w_edge, short* __restrict__ OpA,
    short* __restrict__ OpB, float* __restrict__ ml)
{
    __shared__ sh8 Ks8[2][512];
    __shared__ sh8 Vs8[2][512];

    int cpx = gridDim.x >> 3;     // 512 -> 64
    int swz = (blockIdx.x & 7)*cpx + (blockIdx.x >> 3);
    int w = threadIdx.x >> 6, lane = threadIdx.x & 63;
    int lr = lane & 15, lg = lane >> 4;
    int qb = swz & 7;             // q block of 128 rows
    int h  = (swz >> 3) & 7;
    int b  = (swz >> 6) & 1;
    int ks = swz >> 7;            // 0..3

    const int q0 = qb*128 + w*16;
    const int qrow0 = b*NTOK + q0;
    const int jt0 = ks*4;
    const int bqt = b*64 + qb*8 + w;

    sh8 qf[2];
    #pragma unroll
    for (int s = 0; s < 2; ++s)
        qf[s] = *reinterpret_cast<const sh8*>(qk + (size_t)(qrow0 + lr)*1024 + h*64 + s*32 + lg*8);

    float we2l = w_edge[2*NHEADS + h] * LOG2E;

    float m_i = -1e30f, l_lane = 0.f;
    f32x4 zero = {0.f,0.f,0.f,0.f};
    f32x4 accO[4];
    #pragma unroll
    for (int n = 0; n < 4; ++n) accO[n] = zero;

    const short* kbase = qk + 512 + h*64;
    const short* vbase = vt + (size_t)h*64*2048 + b*NTOK;
    int sr = threadIdx.x >> 3, sg = threadIdx.x & 7;   // 512 threads -> 64 rows
    int sx = (sg ^ (sr & 7)) << 3;

    #define ASTAGE(bf, jt) { \
        aload16(&Ks8[bf][threadIdx.x], kbase + (size_t)(b*NTOK + (jt)*64 + sr)*1024 + sx); \
        aload16(&Vs8[bf][threadIdx.x], vbase + (size_t)sr*2048 + (jt)*64 + sx); \
    }

    short4 rn_reg[2][4];
    unsigned long long mr_reg[2];
    #define RMLOAD(bf, jt) { \
        _Pragma("unroll") \
        for (int n = 0; n < 4; ++n) \
            rn_reg[bf][n] = *reinterpret_cast<const short4*>( \
                &rnP[(size_t)(((bqt*16 + (jt))*4 + n)*256) + lane*4]); \
        mr_reg[bf] = mbP[(size_t)(bqt*16 + (jt))*16 + lr]; \
    }

    ASTAGE(0, jt0)
    RMLOAD(0, jt0)

    #pragma unroll
    for (int t = 0; t < 4; ++t) {
        // outstanding at top: stage(t)=2 (oldest) + rm(t)=5 -> drain stage only
        asm volatile("s_waitcnt vmcnt(5)" ::: "memory");
        __builtin_amdgcn_s_barrier();
        __builtin_amdgcn_sched_barrier(0);
        int buf = t & 1;

        if (t + 1 < 4) {
            ASTAGE(buf ^ 1, jt0 + t + 1)
            RMLOAD(buf ^ 1, jt0 + t + 1)
        }

        // S^T = K Q^T: lane holds S[k = 16n + 4lg + r][q = lr]
        f32x4 Sv[4];
        #pragma unroll
        for (int n = 0; n < 4; ++n) {
            int kcol = n*16 + lr;
            sh8 k0v = Ks8[buf][kcol*8 + (lg       ^ (kcol & 7))];
            sh8 k1v = Ks8[buf][kcol*8 + ((4 + lg) ^ (kcol & 7))];
            Sv[n] = mfma16(k1v, qf[1], mfma16(k0v, qf[0], zero));
        }

        // radial bias (log2 domain)
        #pragma unroll
        for (int n = 0; n < 4; ++n) {
            short4 rn4 = rn_reg[buf][n];
            Sv[n][0] = fmaf(bf2f(rn4.x), we2l, Sv[n][0]);
            Sv[n][1] = fmaf(bf2f(rn4.y), we2l, Sv[n][1]);
            Sv[n][2] = fmaf(bf2f(rn4.z), we2l, Sv[n][2]);
            Sv[n][3] = fmaf(bf2f(rn4.w), we2l, Sv[n][3]);
        }

        // lane-local max + 2-shfl reduce
        float mx = Sv[0][0];
        #pragma unroll
        for (int n = 0; n < 4; ++n)
            #pragma unroll
            for (int r = 0; r < 4; ++r) mx = fmaxf(mx, Sv[n][r]);
        mx = fmaxf(mx, __shfl_xor(mx, 16));
        mx = fmaxf(mx, __shfl_xor(mx, 32));

        // defer-rescale (THR=8 log2 units)
        if (!__all(mx <= m_i + 8.0f)) {
            float mnew = fmaxf(m_i, mx);
            float f = ex2(m_i - mnew);
            m_i = mnew;
            l_lane *= f;
            float fb[4];
            #pragma unroll
            for (int r = 0; r < 4; ++r) fb[r] = __shfl(f, lg*4 + r);
            #pragma unroll
            for (int n = 0; n < 4; ++n)
                #pragma unroll
                for (int r = 0; r < 4; ++r) accO[n][r] *= fb[r];
        }

        // exp, post-exp mask-zero, lane-partial sum, packed bf16 via cvt_pk
        unsigned long long mr = mr_reg[buf];
        float ps = 0.f;
        unsigned pk[8];
        #pragma unroll
        for (int n = 0; n < 4; ++n) {
            float p_[4];
            #pragma unroll
            for (int r = 0; r < 4; ++r) {
                float p = ex2(Sv[n][r] - m_i);
                p = ((mr >> (n*16 + lg*4 + r)) & 1ull) ? 0.f : p;
                ps += p;
                p_[r] = p;
            }
            asm("v_cvt_pk_bf16_f32 %0, %1, %2" : "=v"(pk[2*n])   : "v"(p_[0]), "v"(p_[1]));
            asm("v_cvt_pk_bf16_f32 %0, %1, %2" : "=v"(pk[2*n+1]) : "v"(p_[2]), "v"(p_[3]));
        }
        l_lane += ps;

        // PA fragments via shfl
        int src0 = lr + ((lg & 1) << 5);
        int src1 = src0 + 16;
        sh8 pa[2];
        #pragma unroll
        for (int s = 0; s < 2; ++s) {
            int ns = 2*s + (lg >> 1);
            u32x4 dv;
            dv.x = (unsigned)__shfl((int)pk[2*ns],   src0);
            dv.y = (unsigned)__shfl((int)pk[2*ns+1], src0);
            dv.z = (unsigned)__shfl((int)pk[2*ns],   src1);
            dv.w = (unsigned)__shfl((int)pk[2*ns+1], src1);
            pa[s] = __builtin_bit_cast(sh8, dv);
        }

        // PV
        #pragma unroll
        for (int n = 0; n < 4; ++n) {
            int dcol = n*16 + lr;
            sh8 v0 = Vs8[buf][dcol*8 + (lg       ^ (dcol & 7))];
            sh8 v1 = Vs8[buf][dcol*8 + ((4 + lg) ^ (dcol & 7))];
            accO[n] = mfma16(pa[1], v1, mfma16(pa[0], v0, accO[n]));
        }

        asm volatile("s_waitcnt lgkmcnt(0)" ::: "memory");
    }
    #undef ASTAGE
    #undef RMLOAD

    l_lane += __shfl_xor(l_lane, 16);
    l_lane += __shfl_xor(l_lane, 32);

    short* Op = (ks < 2) ? OpA : OpB;
    #pragma unroll
    for (int r = 0; r < 4; ++r) {
        size_t row = (size_t)((ks & 1)*MTOK + qrow0 + lg*4 + r);
        #pragma unroll
        for (int n = 0; n < 4; ++n)
            Op[row*512 + h*64 + n*16 + lr] = f2bf(accO[n][r]);
    }
    if (lg == 0) {
        size_t mrow = (size_t)(ks*MTOK + qrow0 + lr);
        ml[(mrow*NHEADS + h)*2 + 0] = m_i;
        ml[(mrow*NHEADS + h)*2 + 1] = l_lane;
    }
}

// ---------------- combine 4 KV-split partials -> bf16 O ----------------
__global__ __launch_bounds__(256) void attn_combine4(const short* __restrict__ OpA,
    const short* __restrict__ OpB, const float* __restrict__ ml,
    short* __restrict__ ob)
{
    int idx = blockIdx.x*256 + threadIdx.x;
    int tok = idx >> 7, dd = (idx & 127) * 4;
    int h = dd >> 6;
    float m[4], l[4];
    #pragma unroll
    for (int s = 0; s < 4; ++s) {
        m[s] = ml[(((size_t)s*MTOK + tok)*NHEADS + h)*2 + 0];
        l[s] = ml[(((size_t)s*MTOK + tok)*NHEADS + h)*2 + 1];
    }
    float mm = fmaxf(fmaxf(m[0], m[1]), fmaxf(m[2], m[3]));
    float wsum = 0.f, a0 = 0.f, a1 = 0.f, a2 = 0.f, a3 = 0.f;
    #pragma unroll
    for (int s = 0; s < 4; ++s) {
        float wv = ex2(m[s] - mm);
        wsum += wv * l[s];
        const short* Op = (s < 2) ? OpA : OpB;
        short4 p = *reinterpret_cast<const short4*>(&Op[((size_t)((s&1)*MTOK) + tok)*512 + dd]);
        a0 += bf2f(p.x)*wv; a1 += bf2f(p.y)*wv;
        a2 += bf2f(p.z)*wv; a3 += bf2f(p.w)*wv;
    }
    float inv = 1.f / wsum;
    short4 o;
    o.x = f2bf(a0*inv); o.y = f2bf(a1*inv);
    o.z = f2bf(a2*inv); o.w = f2bf(a3*inv);
    *reinterpret_cast<short4*>(&ob[(size_t)tok*512 + dd]) = o;
}

// -------------------------------------------------------------------------------
extern "C" void kernel_launch(void* const* d_in, const int* in_sizes, int n_in,
                              void* d_out, int out_size, void* d_ws, size_t ws_size,
                              hipStream_t stream)
{
    const float* x      = (const float*)d_in[0];
    const float* coords = (const float*)d_in[1];
    const unsigned char* mask = (const unsigned char*)d_in[2];
    const float* ln1_g = (const float*)d_in[3];
    const float* ln1_b = (const float*)d_in[4];
    const float* w_qkv = (const float*)d_in[5];
    const float* b_qkv = (const float*)d_in[6];
    const float* w_edge= (const float*)d_in[7];
    const float* w_out = (const float*)d_in[8];
    const float* b_out = (const float*)d_in[9];
    const float* ln2_g = (const float*)d_in[10];
    const float* ln2_b = (const float*)d_in[11];
    const float* w1    = (const float*)d_in[12];
    const float* b1    = (const float*)d_in[13];
    const float* w2    = (const float*)d_in[14];
    const float* b2    = (const float*)d_in[15];
    float* out = (float*)d_out;

    char* W = (char*)d_ws;
    const size_t MB = 1024*1024;
    float* x1    = (float*)(W);                    // [0,4M)
    short* qk    = (short*)(W + 4*MB);             // [4M,8M)
    short* vtb   = (short*)(W + 8*MB);             // [8M,10M)
    short* woutT = (short*)(W + 10*MB);            // [10M,10.5M)
    short* xln   = (short*)(W + 10*MB + 512*1024); // [10.5M,12.5M)  (later y)
    short* wqkvT = (short*)(W + 12*MB + 512*1024); // [12.5M,14M)
    short* OpB   = (short*)(W + 10*MB + 512*1024); // [10.5M,14.5M)
    short* OpA   = (short*)(W + 14*MB + 512*1024); // [14.5M,18.5M)
    short* rnP   = (short*)(W + 18*MB + 512*1024); // [18.5M,22.5M)
    float* mlp   = (float*)(W + 22*MB + 512*1024); // [22.5M,23M)
    unsigned long long* mbP = (unsigned long long*)(W + 23*MB); // [23M,23.25M)
    short* ob    = (short*)(W + 6*MB);             // [6M,8M)
    short* y     = xln;
    short* w1T   = (short*)(W + 4*MB);             // [4M,6M)
    short* w2T   = (short*)(W + 8*MB);             // [8M,10M)
    short* hid   = (short*)(W + 14*MB + 512*1024); // [14.5M,22.5M)

    // ---- phase 1 ----
    prep<<<dim3(2048,1,1), 256, 0, stream>>>(coords, mask, rnP, mbP);
    wconv2x<<<dim3(1024,1,1), 256, 0, stream>>>(w_qkv, wqkvT, 512, 1536, 768,
                                                w_out, woutT, 512, 512);
    ln_bf16<<<MTOK, 256, 0, stream>>>(x, ln1_g, ln1_b, xln);
    // fused QKV + V^T: N=1536, v-cols routed through LDS transpose into vtb
    gemm64<0,true,false,true,8,true><<<dim3(768,1,1), 256, 0, stream>>>(
        xln, wqkvT, b_qkv, nullptr, qk, vtb, MTOK, 1536, 512, 24, 1024);
    attn_reg<<<dim3(512,1,1), 512, 0, stream>>>(qk, vtb, rnP, mbP, w_edge, OpA, OpB, mlp);
    attn_combine4<<<dim3(1024,1,1), 256, 0, stream>>>(OpA, OpB, mlp, ob);
    // x1 = ob @ w_out + b_out + x
    gemm32n<1,false,false,8><<<dim3(512,1,1), 256, 0, stream>>>(
        ob, woutT, b_out, x, x1, MTOK, 512, 512, 16);
    // ---- phase 2 ----
    wconv2x<<<dim3(2048,1,1), 256, 0, stream>>>(w1, w1T, 512, 2048, 1024,
                                                w2, w2T, 2048, 512);
    ln_bf16<<<MTOK, 256, 0, stream>>>(x1, ln2_g, ln2_b, y);
    gemm64<2,true,false,false,8,false><<<dim3(1024,1,1), 256, 0, stream>>>(
        y, w1T, b1, nullptr, hid, nullptr, MTOK, 2048, 512, 32, 2048);
    // out = hid @ w2 + b2 + x1
    gemm32n<1,false,false,32><<<dim3(512,1,1), 256, 0, stream>>>(
        hid, w2T, b2, x1, out, MTOK, 512, 2048, 16);
}

// Round 17
// 83.544 us; speedup vs baseline: 2.0002x; 1.0223x over previous
//
#include <hip/hip_runtime.h>
#include <hip/hip_bf16.h>
#include <math.h>

#define NHEADS 8
#define NTOK   1024
#define MTOK   2048

typedef __attribute__((ext_vector_type(8))) short  sh8;
typedef __attribute__((ext_vector_type(8))) __bf16 bf16x8;
typedef __attribute__((ext_vector_type(4))) float  f32x4;
typedef __attribute__((ext_vector_type(4))) unsigned int u32x4;

__device__ __forceinline__ short f2bf(float v) {
    return __builtin_bit_cast(short, __float2bfloat16(v));
}
__device__ __forceinline__ float bf2f(short v) {
    return __builtin_bit_cast(float, ((unsigned)(unsigned short)v) << 16);
}
__device__ __forceinline__ float ex2(float v) {
    return __builtin_amdgcn_exp2f(v);
}
__device__ __forceinline__ f32x4 mfma16(sh8 a, sh8 b, f32x4 c) {
    return __builtin_amdgcn_mfma_f32_16x16x32_bf16(
        __builtin_bit_cast(bf16x8, a), __builtin_bit_cast(bf16x8, b), c, 0, 0, 0);
}
__device__ __forceinline__ void aload16(void* lds, const void* g) {
    __builtin_amdgcn_global_load_lds(
        (const __attribute__((address_space(1))) unsigned int*)g,
        (__attribute__((address_space(3))) unsigned int*)lds, 16, 0, 0);
}

#define LOG2E 1.4426950408889634f

// ---------------- LayerNorm -> bf16 ----------------
__global__ __launch_bounds__(256) void ln_bf16(const float* __restrict__ x,
    const float* __restrict__ g, const float* __restrict__ bta, short* __restrict__ y)
{
    int row = blockIdx.x, t = threadIdx.x;
    const float* xr = x + (size_t)row * 512;
    float2 v = *reinterpret_cast<const float2*>(&xr[t*2]);
    float s = v.x + v.y, ss = v.x*v.x + v.y*v.y;
    #pragma unroll
    for (int m = 1; m < 64; m <<= 1) { s += __shfl_xor(s, m); ss += __shfl_xor(ss, m); }
    __shared__ float red[8];
    int wid = t >> 6, lane = t & 63;
    if (!lane) { red[wid] = s; red[4+wid] = ss; }
    __syncthreads();
    s = red[0]+red[1]+red[2]+red[3]; ss = red[4]+red[5]+red[6]+red[7];
    float mu = s*(1.f/512), var = ss*(1.f/512) - mu*mu, rs = rsqrtf(var + 1e-5f);
    float2 gg = *reinterpret_cast<const float2*>(&g[t*2]);
    float2 bb = *reinterpret_cast<const float2*>(&bta[t*2]);
    short2 o; o.x = f2bf((v.x-mu)*rs*gg.x + bb.x); o.y = f2bf((v.y-mu)*rs*gg.y + bb.y);
    *reinterpret_cast<short2*>(&y[(size_t)row*512 + t*2]) = o;
}

// ---------------- merged: two fp32 W[K][N] -> bf16 W^T[N][K] transposes --------
__global__ __launch_bounds__(256) void wconv2x(
    const float* __restrict__ W0, short* __restrict__ WT0, int K0, int N0, int nb0,
    const float* __restrict__ W1, short* __restrict__ WT1, int K1, int N1)
{
    const float* W; short* WT; int K, N, bid;
    if ((int)blockIdx.x < nb0) { W = W0; WT = WT0; K = K0; N = N0; bid = blockIdx.x; }
    else                       { W = W1; WT = WT1; K = K1; N = N1; bid = blockIdx.x - nb0; }
    int nbx = N >> 5;
    int bn = (bid % nbx) * 32, bk = (bid / nbx) * 32;
    __shared__ float t[32][33];
    int c = threadIdx.x & 31, r8 = threadIdx.x >> 5;
    #pragma unroll
    for (int i = 0; i < 4; ++i) {
        int r = r8 + i*8;
        t[r][c] = W[(size_t)(bk + r)*N + bn + c];
    }
    __syncthreads();
    #pragma unroll
    for (int i = 0; i < 4; ++i) {
        int r = r8 + i*8;
        WT[(size_t)(bn + r)*K + bk + c] = f2bf(t[c][r]);
    }
}

// ---------------- merged prep (rn/mask tables) + phase-1 weight transposes -----
__global__ __launch_bounds__(256) void prep_wconv(
    const float* __restrict__ coords, const unsigned char* __restrict__ mask,
    short* __restrict__ rnP, unsigned long long* __restrict__ mbP,
    const float* __restrict__ W0, short* __restrict__ WT0,
    const float* __restrict__ W1, short* __restrict__ WT1)
{
    if ((int)blockIdx.x >= 2048) {
        // weight transpose: blocks [2048,3072): 768 for w_qkv, 256 for w_out
        int bid = blockIdx.x - 2048;
        const float* W; short* WT; int N;
        if (bid < 768) { W = W0; WT = WT0; N = 1536; }
        else           { W = W1; WT = WT1; N = 512; bid -= 768; }
        int nbx = N >> 5;
        int bn = (bid % nbx) * 32, bk = (bid / nbx) * 32;
        __shared__ float t[32][33];
        int c = threadIdx.x & 31, r8 = threadIdx.x >> 5;
        #pragma unroll
        for (int i = 0; i < 4; ++i) {
            int r = r8 + i*8;
            t[r][c] = W[(size_t)(bk + r)*N + bn + c];
        }
        __syncthreads();
        #pragma unroll
        for (int i = 0; i < 4; ++i) {
            int r = r8 + i*8;
            WT[(size_t)(bn + r)*512 + bk + c] = f2bf(t[c][r]);
        }
        return;
    }
    __shared__ float2 kc_s[64];
    __shared__ float2 qc_s[16];
    int bid = blockIdx.x;                // bqt*16 + jt
    int bqt = bid >> 4, jt = bid & 15;
    int b = bqt >> 6, qt = bqt & 63;
    int t = threadIdx.x, w = t >> 6, lane = t & 63;
    int lr = lane & 15, lg = lane >> 4;

    if (t < 64)            kc_s[t]      = *reinterpret_cast<const float2*>(&coords[(size_t)(b*1024 + jt*64 + t)*2]);
    else if (t < 80)       qc_s[t - 64] = *reinterpret_cast<const float2*>(&coords[(size_t)(b*1024 + qt*16 + (t - 64))*2]);
    __syncthreads();

    float2 qc = qc_s[lr];
    short4 o;
    short* op = &o.x;
    #pragma unroll
    for (int r = 0; r < 4; ++r) {
        float2 kc = kc_s[w*16 + lg*4 + r];
        float dx = qc.x - kc.x, dy = qc.y - kc.y;
        op[r] = f2bf(sqrtf(dx*dx + dy*dy));
    }
    *reinterpret_cast<short4*>(&rnP[(size_t)((bid*4 + w)*256) + lane*4]) = o;

    #pragma unroll
    for (int i = 0; i < 4; ++i) {
        int q = w*4 + i;
        unsigned char v = mask[(size_t)(b*1024 + qt*16 + q)*NTOK + jt*64 + lane];
        unsigned long long bits = __ballot(v != 0);
        if (!lane) mbP[(size_t)bid*16 + q] = bits;
    }
}

// ---------------- bf16 MFMA GEMM, 64x64 tile, BK=64, 3-stage counted-vmcnt ----
template<int EPI, bool OUTBF, bool BIAS_ROW, bool QSC, int NT, bool VTOUT>
__global__ __launch_bounds__(256) void gemm64(
    const short* __restrict__ A, const short* __restrict__ BT,
    const float* __restrict__ bias, const float* __restrict__ res,
    void* __restrict__ Cout, short* __restrict__ vtx,
    int M, int N, int K, int nbx, int ldc)
{
    __shared__ sh8 As8[3][512];
    __shared__ sh8 Bs8[3][512];
    int tid = threadIdx.x;
    int w = tid >> 6, lane = tid & 63, lr = lane & 15, lg = lane >> 4;
    int wr = w >> 1, wc = w & 1;
    int cpx = gridDim.x >> 3;
    int swz = (blockIdx.x & 7)*cpx + (blockIdx.x >> 3);
    int bx = swz % nbx, by = swz / nbx;
    int bm0 = by*64, bn0 = bx*64;

    f32x4 zero = {0.f,0.f,0.f,0.f};
    f32x4 acc[2][2];
    #pragma unroll
    for (int m = 0; m < 2; ++m)
        #pragma unroll
        for (int n = 0; n < 2; ++n) acc[m][n] = zero;

    #define STAGE(buf, k0) { \
        _Pragma("unroll") \
        for (int it = 0; it < 2; ++it) { \
            int s = tid + it*256; \
            int r = s >> 3, g = s & 7; \
            int ksw = (k0) + ((g ^ (r & 7)) << 3); \
            aload16(&As8[buf][s], A  + (size_t)(bm0 + r)*K + ksw); \
            aload16(&Bs8[buf][s], BT + (size_t)(bn0 + r)*K + ksw); \
        } }

    STAGE(0, 0)
    if (NT > 1) STAGE(1, 64)

    #pragma unroll
    for (int t = 0; t < NT; ++t) {
        if (t + 1 < NT) asm volatile("s_waitcnt vmcnt(4)" ::: "memory");
        else            asm volatile("s_waitcnt vmcnt(0)" ::: "memory");
        __builtin_amdgcn_s_barrier();
        __builtin_amdgcn_sched_barrier(0);
        int buf = t % 3;
        sh8 af[2][2], bfv[2][2];
        #pragma unroll
        for (int m = 0; m < 2; ++m) {
            int R = wr*32 + m*16 + lr;
            #pragma unroll
            for (int s = 0; s < 2; ++s) af[m][s] = As8[buf][R*8 + ((s*4+lg) ^ (R & 7))];
        }
        #pragma unroll
        for (int n = 0; n < 2; ++n) {
            int R = wc*32 + n*16 + lr;
            #pragma unroll
            for (int s = 0; s < 2; ++s) bfv[n][s] = Bs8[buf][R*8 + ((s*4+lg) ^ (R & 7))];
        }
        if (t + 2 < NT) STAGE((t+2)%3, (t+2)*64)
        #pragma unroll
        for (int m = 0; m < 2; ++m)
            #pragma unroll
            for (int n = 0; n < 2; ++n)
                #pragma unroll
                for (int s = 0; s < 2; ++s)
                    acc[m][n] = mfma16(af[m][s], bfv[n][s], acc[m][n]);
        asm volatile("s_waitcnt lgkmcnt(0)" ::: "memory");
    }
    #undef STAGE

    if (VTOUT && bn0 >= 1024) {
        __syncthreads();
        short* tb = (short*)&As8[0][0];   // 64 x 68 shorts
        #pragma unroll
        for (int m = 0; m < 2; ++m)
            #pragma unroll
            for (int n = 0; n < 2; ++n)
                #pragma unroll
                for (int r = 0; r < 4; ++r) {
                    int row = wr*32 + m*16 + lg*4 + r;
                    int col = wc*32 + n*16 + lr;
                    float v = acc[m][n][r] + bias[bn0 + col];
                    tb[col*68 + row] = f2bf(v);
                }
        __syncthreads();
        int vd = tid >> 2, t0 = (tid & 3) << 4;
        #pragma unroll
        for (int i = 0; i < 4; ++i) {
            short4 s4 = *reinterpret_cast<short4*>(&tb[vd*68 + t0 + i*4]);
            *reinterpret_cast<short4*>(&vtx[(size_t)(bn0 - 1024 + vd)*2048 + bm0 + t0 + i*4]) = s4;
        }
        return;
    }

    #pragma unroll
    for (int m = 0; m < 2; ++m) {
        #pragma unroll
        for (int n = 0; n < 2; ++n) {
            #pragma unroll
            for (int r = 0; r < 4; ++r) {
                int row = bm0 + wr*32 + m*16 + lg*4 + r;
                int col = bn0 + wc*32 + n*16 + lr;
                float v = acc[m][n][r] + (BIAS_ROW ? bias[row] : bias[col]);
                if (QSC && col < 512) v *= (0.125f * LOG2E);
                if (EPI == 1) v += res[(size_t)row*ldc + col];
                if (EPI == 2) v = 0.5f * v * (1.0f + erff(v * 0.70710678f));
                if (OUTBF) ((short*)Cout)[(size_t)row*ldc + col] = f2bf(v);
                else       ((float*)Cout)[(size_t)row*ldc + col] = v;
            }
        }
    }
}

// ---------------- bf16 MFMA GEMM, 64x32 tile ----------------
template<int EPI, bool OUTBF, bool BIAS_ROW, int NT>
__global__ __launch_bounds__(256) void gemm32n(
    const short* __restrict__ A, const short* __restrict__ BT,
    const float* __restrict__ bias, const float* __restrict__ res,
    void* __restrict__ Cout, int M, int N, int K, int nbx)
{
    __shared__ sh8 As8[3][512];
    __shared__ sh8 Bs8[3][256];
    int tid = threadIdx.x;
    int w = tid >> 6, lane = tid & 63, lr = lane & 15, lg = lane >> 4;
    int cpx = gridDim.x >> 3;
    int swz = (blockIdx.x & 7)*cpx + (blockIdx.x >> 3);
    int bx = swz % nbx, by = swz / nbx;
    int bm0 = by*64, bn0 = bx*32;

    f32x4 zero = {0.f,0.f,0.f,0.f};
    f32x4 acc[2];
    acc[0] = zero; acc[1] = zero;

    #define STAGE32(buf, k0) { \
        _Pragma("unroll") \
        for (int it = 0; it < 2; ++it) { \
            int s = tid + it*256; \
            int r = s >> 3, g = s & 7; \
            int ksw = (k0) + ((g ^ (r & 7)) << 3); \
            aload16(&As8[buf][s], A + (size_t)(bm0 + r)*K + ksw); \
        } \
        { int r = tid >> 3, g = tid & 7; \
          int ksw = (k0) + ((g ^ (r & 7)) << 3); \
          aload16(&Bs8[buf][tid], BT + (size_t)(bn0 + r)*K + ksw); } }

    STAGE32(0, 0)
    if (NT > 1) STAGE32(1, 64)

    #pragma unroll
    for (int t = 0; t < NT; ++t) {
        if (t + 1 < NT) asm volatile("s_waitcnt vmcnt(3)" ::: "memory");
        else            asm volatile("s_waitcnt vmcnt(0)" ::: "memory");
        __builtin_amdgcn_s_barrier();
        __builtin_amdgcn_sched_barrier(0);
        int buf = t % 3;
        sh8 af[2], bfv[2][2];
        int Ra = w*16 + lr;
        #pragma unroll
        for (int s = 0; s < 2; ++s) af[s] = As8[buf][Ra*8 + ((s*4+lg) ^ (Ra & 7))];
        #pragma unroll
        for (int n = 0; n < 2; ++n) {
            int R = n*16 + lr;
            #pragma unroll
            for (int s = 0; s < 2; ++s) bfv[n][s] = Bs8[buf][R*8 + ((s*4+lg) ^ (R & 7))];
        }
        if (t + 2 < NT) STAGE32((t+2)%3, (t+2)*64)
        #pragma unroll
        for (int n = 0; n < 2; ++n)
            #pragma unroll
            for (int s = 0; s < 2; ++s)
                acc[n] = mfma16(af[s], bfv[n][s], acc[n]);
        asm volatile("s_waitcnt lgkmcnt(0)" ::: "memory");
    }
    #undef STAGE32

    #pragma unroll
    for (int n = 0; n < 2; ++n) {
        #pragma unroll
        for (int r = 0; r < 4; ++r) {
            int row = bm0 + w*16 + lg*4 + r;
            int col = bn0 + n*16 + lr;
            float v = acc[n][r] + (BIAS_ROW ? bias[row] : bias[col]);
            if (EPI == 1) v += res[(size_t)row*N + col];
            if (EPI == 2) v = 0.5f * v * (1.0f + erff(v * 0.70710678f));
            if (OUTBF) ((short*)Cout)[(size_t)row*N + col] = f2bf(v);
            else       ((float*)Cout)[(size_t)row*N + col] = v;
        }
    }
}

// ---------------- MFMA flash attention: ALL 4 KV tiles staged upfront ---------
// 512 blocks x 512 threads (8 waves). ONE vmcnt(0) + ONE barrier total; the 4
// tile iterations are pure LDS/VALU/MFMA with no inter-wave sync -> tiles'
// QK/softmax/PV chains overlap freely across waves.
__global__ __launch_bounds__(512) void attn_reg(
    const short* __restrict__ qk, const short* __restrict__ vt,
    const short* __restrict__ rnP, const unsigned long long* __restrict__ mbP,
    const float* __restrict__ w_edge, short* __restrict__ OpA,
    short* __restrict__ OpB, float* __restrict__ ml)
{
    __shared__ sh8 Ks8[4][512];   // 32 KB
    __shared__ sh8 Vs8[4][512];   // 32 KB

    int cpx = gridDim.x >> 3;     // 64
    int swz = (blockIdx.x & 7)*cpx + (blockIdx.x >> 3);
    int w = threadIdx.x >> 6, lane = threadIdx.x & 63;
    int lr = lane & 15, lg = lane >> 4;
    int qb = swz & 7;             // q block of 128 rows
    int h  = (swz >> 3) & 7;
    int b  = (swz >> 6) & 1;
    int ks = swz >> 7;            // 0..3

    const int q0 = qb*128 + w*16;
    const int qrow0 = b*NTOK + q0;
    const int jt0 = ks*4;
    const int bqt = b*64 + qb*8 + w;

    sh8 qf[2];
    #pragma unroll
    for (int s = 0; s < 2; ++s)
        qf[s] = *reinterpret_cast<const sh8*>(qk + (size_t)(qrow0 + lr)*1024 + h*64 + s*32 + lg*8);

    float we2l = w_edge[2*NHEADS + h] * LOG2E;

    float m_i = -1e30f, l_lane = 0.f;
    f32x4 zero = {0.f,0.f,0.f,0.f};
    f32x4 accO[4];
    #pragma unroll
    for (int n = 0; n < 4; ++n) accO[n] = zero;

    const short* kbase = qk + 512 + h*64;
    const short* vbase = vt + (size_t)h*64*2048 + b*NTOK;
    int sr = threadIdx.x >> 3, sg = threadIdx.x & 7;   // 512 threads -> 64 rows
    int sx = (sg ^ (sr & 7)) << 3;

    // stage ALL 4 tiles (8 loads/thread) + prefetch all rn/mask into regs
    #pragma unroll
    for (int t = 0; t < 4; ++t) {
        aload16(&Ks8[t][threadIdx.x], kbase + (size_t)(b*NTOK + (jt0 + t)*64 + sr)*1024 + sx);
        aload16(&Vs8[t][threadIdx.x], vbase + (size_t)sr*2048 + (jt0 + t)*64 + sx);
    }
    short4 rn_reg[4][4];
    unsigned long long mr_reg[4];
    #pragma unroll
    for (int t = 0; t < 4; ++t) {
        #pragma unroll
        for (int n = 0; n < 4; ++n)
            rn_reg[t][n] = *reinterpret_cast<const short4*>(
                &rnP[(size_t)(((bqt*16 + jt0 + t)*4 + n)*256) + lane*4]);
        mr_reg[t] = mbP[(size_t)(bqt*16 + jt0 + t)*16 + lr];
    }

    asm volatile("s_waitcnt vmcnt(0)" ::: "memory");
    __builtin_amdgcn_s_barrier();

    #pragma unroll
    for (int t = 0; t < 4; ++t) {
        // S^T = K Q^T: lane holds S[k = 16n + 4lg + r][q = lr]
        f32x4 Sv[4];
        #pragma unroll
        for (int n = 0; n < 4; ++n) {
            int kcol = n*16 + lr;
            sh8 k0v = Ks8[t][kcol*8 + (lg       ^ (kcol & 7))];
            sh8 k1v = Ks8[t][kcol*8 + ((4 + lg) ^ (kcol & 7))];
            Sv[n] = mfma16(k1v, qf[1], mfma16(k0v, qf[0], zero));
        }

        // radial bias (log2 domain)
        #pragma unroll
        for (int n = 0; n < 4; ++n) {
            short4 rn4 = rn_reg[t][n];
            Sv[n][0] = fmaf(bf2f(rn4.x), we2l, Sv[n][0]);
            Sv[n][1] = fmaf(bf2f(rn4.y), we2l, Sv[n][1]);
            Sv[n][2] = fmaf(bf2f(rn4.z), we2l, Sv[n][2]);
            Sv[n][3] = fmaf(bf2f(rn4.w), we2l, Sv[n][3]);
        }

        // lane-local max + 2-shfl reduce
        float mx = Sv[0][0];
        #pragma unroll
        for (int n = 0; n < 4; ++n)
            #pragma unroll
            for (int r = 0; r < 4; ++r) mx = fmaxf(mx, Sv[n][r]);
        mx = fmaxf(mx, __shfl_xor(mx, 16));
        mx = fmaxf(mx, __shfl_xor(mx, 32));

        // defer-rescale (THR=8 log2 units)
        if (!__all(mx <= m_i + 8.0f)) {
            float mnew = fmaxf(m_i, mx);
            float f = ex2(m_i - mnew);
            m_i = mnew;
            l_lane *= f;
            float fb[4];
            #pragma unroll
            for (int r = 0; r < 4; ++r) fb[r] = __shfl(f, lg*4 + r);
            #pragma unroll
            for (int n = 0; n < 4; ++n)
                #pragma unroll
                for (int r = 0; r < 4; ++r) accO[n][r] *= fb[r];
        }

        // exp, post-exp mask-zero, lane-partial sum, packed bf16 via cvt_pk
        unsigned long long mr = mr_reg[t];
        float ps = 0.f;
        unsigned pk[8];
        #pragma unroll
        for (int n = 0; n < 4; ++n) {
            float p_[4];
            #pragma unroll
            for (int r = 0; r < 4; ++r) {
                float p = ex2(Sv[n][r] - m_i);
                p = ((mr >> (n*16 + lg*4 + r)) & 1ull) ? 0.f : p;
                ps += p;
                p_[r] = p;
            }
            asm("v_cvt_pk_bf16_f32 %0, %1, %2" : "=v"(pk[2*n])   : "v"(p_[0]), "v"(p_[1]));
            asm("v_cvt_pk_bf16_f32 %0, %1, %2" : "=v"(pk[2*n+1]) : "v"(p_[2]), "v"(p_[3]));
        }
        l_lane += ps;

        // PA fragments via shfl
        int src0 = lr + ((lg & 1) << 5);
        int src1 = src0 + 16;
        sh8 pa[2];
        #pragma unroll
        for (int s = 0; s < 2; ++s) {
            int ns = 2*s + (lg >> 1);
            u32x4 dv;
            dv.x = (unsigned)__shfl((int)pk[2*ns],   src0);
            dv.y = (unsigned)__shfl((int)pk[2*ns+1], src0);
            dv.z = (unsigned)__shfl((int)pk[2*ns],   src1);
            dv.w = (unsigned)__shfl((int)pk[2*ns+1], src1);
            pa[s] = __builtin_bit_cast(sh8, dv);
        }

        // PV
        #pragma unroll
        for (int n = 0; n < 4; ++n) {
            int dcol = n*16 + lr;
            sh8 v0 = Vs8[t][dcol*8 + (lg       ^ (dcol & 7))];
            sh8 v1 = Vs8[t][dcol*8 + ((4 + lg) ^ (dcol & 7))];
            accO[n] = mfma16(pa[1], v1, mfma16(pa[0], v0, accO[n]));
        }
    }

    l_lane += __shfl_xor(l_lane, 16);
    l_lane += __shfl_xor(l_lane, 32);

    short* Op = (ks < 2) ? OpA : OpB;
    #pragma unroll
    for (int r = 0; r < 4; ++r) {
        size_t row = (size_t)((ks & 1)*MTOK + qrow0 + lg*4 + r);
        #pragma unroll
        for (int n = 0; n < 4; ++n)
            Op[row*512 + h*64 + n*16 + lr] = f2bf(accO[n][r]);
    }
    if (lg == 0) {
        size_t mrow = (size_t)(ks*MTOK + qrow0 + lr);
        ml[(mrow*NHEADS + h)*2 + 0] = m_i;
        ml[(mrow*NHEADS + h)*2 + 1] = l_lane;
    }
}

// ---------------- combine 4 KV-split partials -> bf16 O ----------------
__global__ __launch_bounds__(256) void attn_combine4(const short* __restrict__ OpA,
    const short* __restrict__ OpB, const float* __restrict__ ml,
    short* __restrict__ ob)
{
    int idx = blockIdx.x*256 + threadIdx.x;
    int tok = idx >> 7, dd = (idx & 127) * 4;
    int h = dd >> 6;
    float m[4], l[4];
    #pragma unroll
    for (int s = 0; s < 4; ++s) {
        m[s] = ml[(((size_t)s*MTOK + tok)*NHEADS + h)*2 + 0];
        l[s] = ml[(((size_t)s*MTOK + tok)*NHEADS + h)*2 + 1];
    }
    float mm = fmaxf(fmaxf(m[0], m[1]), fmaxf(m[2], m[3]));
    float wsum = 0.f, a0 = 0.f, a1 = 0.f, a2 = 0.f, a3 = 0.f;
    #pragma unroll
    for (int s = 0; s < 4; ++s) {
        float wv = ex2(m[s] - mm);
        wsum += wv * l[s];
        const short* Op = (s < 2) ? OpA : OpB;
        short4 p = *reinterpret_cast<const short4*>(&Op[((size_t)((s&1)*MTOK) + tok)*512 + dd]);
        a0 += bf2f(p.x)*wv; a1 += bf2f(p.y)*wv;
        a2 += bf2f(p.z)*wv; a3 += bf2f(p.w)*wv;
    }
    float inv = 1.f / wsum;
    short4 o;
    o.x = f2bf(a0*inv); o.y = f2bf(a1*inv);
    o.z = f2bf(a2*inv); o.w = f2bf(a3*inv);
    *reinterpret_cast<short4*>(&ob[(size_t)tok*512 + dd]) = o;
}

// -------------------------------------------------------------------------------
extern "C" void kernel_launch(void* const* d_in, const int* in_sizes, int n_in,
                              void* d_out, int out_size, void* d_ws, size_t ws_size,
                              hipStream_t stream)
{
    const float* x      = (const float*)d_in[0];
    const float* coords = (const float*)d_in[1];
    const unsigned char* mask = (const unsigned char*)d_in[2];
    const float* ln1_g = (const float*)d_in[3];
    const float* ln1_b = (const float*)d_in[4];
    const float* w_qkv = (const float*)d_in[5];
    const float* b_qkv = (const float*)d_in[6];
    const float* w_edge= (const float*)d_in[7];
    const float* w_out = (const float*)d_in[8];
    const float* b_out = (const float*)d_in[9];
    const float* ln2_g = (const float*)d_in[10];
    const float* ln2_b = (const float*)d_in[11];
    const float* w1    = (const float*)d_in[12];
    const float* b1    = (const float*)d_in[13];
    const float* w2    = (const float*)d_in[14];
    const float* b2    = (const float*)d_in[15];
    float* out = (float*)d_out;

    char* W = (char*)d_ws;
    const size_t MB = 1024*1024;
    float* x1    = (float*)(W);                    // [0,4M)
    short* qk    = (short*)(W + 4*MB);             // [4M,8M)
    short* vtb   = (short*)(W + 8*MB);             // [8M,10M)
    short* woutT = (short*)(W + 10*MB);            // [10M,10.5M)
    short* xln   = (short*)(W + 10*MB + 512*1024); // [10.5M,12.5M)  (later y)
    short* wqkvT = (short*)(W + 12*MB + 512*1024); // [12.5M,14M)
    short* OpB   = (short*)(W + 10*MB + 512*1024); // [10.5M,14.5M)
    short* OpA   = (short*)(W + 14*MB + 512*1024); // [14.5M,18.5M)
    short* rnP   = (short*)(W + 18*MB + 512*1024); // [18.5M,22.5M)
    float* mlp   = (float*)(W + 22*MB + 512*1024); // [22.5M,23M)
    unsigned long long* mbP = (unsigned long long*)(W + 23*MB); // [23M,23.25M)
    short* ob    = (short*)(W + 6*MB);             // [6M,8M)
    short* y     = xln;
    short* w1T   = (short*)(W + 4*MB);             // [4M,6M)
    short* w2T   = (short*)(W + 8*MB);             // [8M,10M)
    short* hid   = (short*)(W + 14*MB + 512*1024); // [14.5M,22.5M)

    // ---- phase 1 ----
    prep_wconv<<<dim3(3072,1,1), 256, 0, stream>>>(coords, mask, rnP, mbP,
                                                   w_qkv, wqkvT, w_out, woutT);
    ln_bf16<<<MTOK, 256, 0, stream>>>(x, ln1_g, ln1_b, xln);
    // fused QKV + V^T: N=1536, v-cols routed through LDS transpose into vtb
    gemm64<0,true,false,true,8,true><<<dim3(768,1,1), 256, 0, stream>>>(
        xln, wqkvT, b_qkv, nullptr, qk, vtb, MTOK, 1536, 512, 24, 1024);
    attn_reg<<<dim3(512,1,1), 512, 0, stream>>>(qk, vtb, rnP, mbP, w_edge, OpA, OpB, mlp);
    attn_combine4<<<dim3(1024,1,1), 256, 0, stream>>>(OpA, OpB, mlp, ob);
    // x1 = ob @ w_out + b_out + x
    gemm32n<1,false,false,8><<<dim3(512,1,1), 256, 0, stream>>>(
        ob, woutT, b_out, x, x1, MTOK, 512, 512, 16);
    // ---- phase 2 ----
    wconv2x<<<dim3(2048,1,1), 256, 0, stream>>>(w1, w1T, 512, 2048, 1024,
                                                w2, w2T, 2048, 512);
    ln_bf16<<<MTOK, 256, 0, stream>>>(x1, ln2_g, ln2_b, y);
    gemm64<2,true,false,false,8,false><<<dim3(1024,1,1), 256, 0, stream>>>(
        y, w1T, b1, nullptr, hid, nullptr, MTOK, 2048, 512, 32, 2048);
    // out = hid @ w2 + b2 + x1
    gemm32n<1,false,false,32><<<dim3(512,1,1), 256, 0, stream>>>(
        hid, w2T, b2, x1, out, MTOK, 512, 2048, 16);
}

// Round 18
// 79.411 us; speedup vs baseline: 2.1043x; 1.0521x over previous
//
#include <hip/hip_runtime.h>
#include <hip/hip_bf16.h>
#include <math.h>

#define NHEADS 8
#define NTOK   1024
#define MTOK   2048

typedef __attribute__((ext_vector_type(8))) short  sh8;
typedef __attribute__((ext_vector_type(8))) __bf16 bf16x8;
typedef __attribute__((ext_vector_type(4))) float  f32x4;
typedef __attribute__((ext_vector_type(4))) unsigned int u32x4;

__device__ __forceinline__ short f2bf(float v) {
    return __builtin_bit_cast(short, __float2bfloat16(v));
}
__device__ __forceinline__ float bf2f(short v) {
    return __builtin_bit_cast(float, ((unsigned)(unsigned short)v) << 16);
}
__device__ __forceinline__ float ex2(float v) {
    return __builtin_amdgcn_exp2f(v);
}
__device__ __forceinline__ f32x4 mfma16(sh8 a, sh8 b, f32x4 c) {
    return __builtin_amdgcn_mfma_f32_16x16x32_bf16(
        __builtin_bit_cast(bf16x8, a), __builtin_bit_cast(bf16x8, b), c, 0, 0, 0);
}
__device__ __forceinline__ void aload16(void* lds, const void* g) {
    __builtin_amdgcn_global_load_lds(
        (const __attribute__((address_space(1))) unsigned int*)g,
        (__attribute__((address_space(3))) unsigned int*)lds, 16, 0, 0);
}

#define LOG2E 1.4426950408889634f

// ---------------- LayerNorm row body (shared by front & ln2) ----------------
__device__ __forceinline__ void ln_row(const float* __restrict__ x,
    const float* __restrict__ g, const float* __restrict__ bta,
    short* __restrict__ y, int row, int t)
{
    const float* xr = x + (size_t)row * 512;
    float2 v = *reinterpret_cast<const float2*>(&xr[t*2]);
    float s = v.x + v.y, ss = v.x*v.x + v.y*v.y;
    #pragma unroll
    for (int m = 1; m < 64; m <<= 1) { s += __shfl_xor(s, m); ss += __shfl_xor(ss, m); }
    __shared__ float red[8];
    int wid = t >> 6, lane = t & 63;
    if (!lane) { red[wid] = s; red[4+wid] = ss; }
    __syncthreads();
    s = red[0]+red[1]+red[2]+red[3]; ss = red[4]+red[5]+red[6]+red[7];
    float mu = s*(1.f/512), var = ss*(1.f/512) - mu*mu, rs = rsqrtf(var + 1e-5f);
    float2 gg = *reinterpret_cast<const float2*>(&g[t*2]);
    float2 bb = *reinterpret_cast<const float2*>(&bta[t*2]);
    short2 o; o.x = f2bf((v.x-mu)*rs*gg.x + bb.x); o.y = f2bf((v.y-mu)*rs*gg.y + bb.y);
    *reinterpret_cast<short2*>(&y[(size_t)row*512 + t*2]) = o;
}

__global__ __launch_bounds__(256) void ln_bf16(const float* __restrict__ x,
    const float* __restrict__ g, const float* __restrict__ bta, short* __restrict__ y)
{
    ln_row(x, g, bta, y, blockIdx.x, threadIdx.x);
}

// ---------------- weight transpose body: W[K][N] f32 -> WT[N][K] bf16 ----------
__device__ __forceinline__ void wconv_body(const float* __restrict__ W,
    short* __restrict__ WT, int K, int N, int bid)
{
    int nbx = N >> 5;
    int bn = (bid % nbx) * 32, bk = (bid / nbx) * 32;
    __shared__ float t[32][33];
    int c = threadIdx.x & 31, r8 = threadIdx.x >> 5;
    #pragma unroll
    for (int i = 0; i < 4; ++i) {
        int r = r8 + i*8;
        t[r][c] = W[(size_t)(bk + r)*N + bn + c];
    }
    __syncthreads();
    #pragma unroll
    for (int i = 0; i < 4; ++i) {
        int r = r8 + i*8;
        WT[(size_t)(bn + r)*K + bk + c] = f2bf(t[c][r]);
    }
}

// ---------------- FRONT mega-kernel: prep + all weight transposes + LN1 --------
// [0,2048)    : rn/mask tables (block = bqt*16 + jt)
// [2048,3072) : w_qkv (768) + w_out (256) transposes
// [3072,5120) : w1 (1024) + w2 (1024) transposes
// [5120,7168) : LN1 rows
__global__ __launch_bounds__(256) void front(
    const float* __restrict__ coords, const unsigned char* __restrict__ mask,
    short* __restrict__ rnP, unsigned long long* __restrict__ mbP,
    const float* __restrict__ w_qkv, short* __restrict__ wqkvT,
    const float* __restrict__ w_out, short* __restrict__ woutT,
    const float* __restrict__ w1, short* __restrict__ w1T,
    const float* __restrict__ w2, short* __restrict__ w2T,
    const float* __restrict__ x, const float* __restrict__ ln1_g,
    const float* __restrict__ ln1_b, short* __restrict__ xln)
{
    int bid = blockIdx.x;
    if (bid >= 5120) { ln_row(x, ln1_g, ln1_b, xln, bid - 5120, threadIdx.x); return; }
    if (bid >= 4096) { wconv_body(w2, w2T, 2048, 512, bid - 4096); return; }
    if (bid >= 3072) { wconv_body(w1, w1T, 512, 2048, bid - 3072); return; }
    if (bid >= 2048) {
        int b2 = bid - 2048;
        if (b2 < 768) wconv_body(w_qkv, wqkvT, 512, 1536, b2);
        else          wconv_body(w_out, woutT, 512, 512, b2 - 768);
        return;
    }
    // prep: rn + mask tables
    __shared__ float2 kc_s[64];
    __shared__ float2 qc_s[16];
    int bqt = bid >> 4, jt = bid & 15;
    int b = bqt >> 6, qt = bqt & 63;
    int t = threadIdx.x, w = t >> 6, lane = t & 63;
    int lr = lane & 15, lg = lane >> 4;

    if (t < 64)       kc_s[t]      = *reinterpret_cast<const float2*>(&coords[(size_t)(b*1024 + jt*64 + t)*2]);
    else if (t < 80)  qc_s[t - 64] = *reinterpret_cast<const float2*>(&coords[(size_t)(b*1024 + qt*16 + (t - 64))*2]);
    __syncthreads();

    float2 qc = qc_s[lr];
    short4 o;
    short* op = &o.x;
    #pragma unroll
    for (int r = 0; r < 4; ++r) {
        float2 kc = kc_s[w*16 + lg*4 + r];
        float dx = qc.x - kc.x, dy = qc.y - kc.y;
        op[r] = f2bf(sqrtf(dx*dx + dy*dy));
    }
    *reinterpret_cast<short4*>(&rnP[(size_t)((bid*4 + w)*256) + lane*4]) = o;

    #pragma unroll
    for (int i = 0; i < 4; ++i) {
        int q = w*4 + i;
        unsigned char v = mask[(size_t)(b*1024 + qt*16 + q)*NTOK + jt*64 + lane];
        unsigned long long bits = __ballot(v != 0);
        if (!lane) mbP[(size_t)bid*16 + q] = bits;
    }
}

// ---------------- bf16 MFMA GEMM, 64x64 tile, BK=64, 3-stage counted-vmcnt ----
template<int EPI, bool OUTBF, bool BIAS_ROW, bool QSC, int NT, bool VTOUT>
__global__ __launch_bounds__(256) void gemm64(
    const short* __restrict__ A, const short* __restrict__ BT,
    const float* __restrict__ bias, const float* __restrict__ res,
    void* __restrict__ Cout, short* __restrict__ vtx,
    int M, int N, int K, int nbx, int ldc)
{
    __shared__ sh8 As8[3][512];
    __shared__ sh8 Bs8[3][512];
    int tid = threadIdx.x;
    int w = tid >> 6, lane = tid & 63, lr = lane & 15, lg = lane >> 4;
    int wr = w >> 1, wc = w & 1;
    int cpx = gridDim.x >> 3;
    int swz = (blockIdx.x & 7)*cpx + (blockIdx.x >> 3);
    int bx = swz % nbx, by = swz / nbx;
    int bm0 = by*64, bn0 = bx*64;

    f32x4 zero = {0.f,0.f,0.f,0.f};
    f32x4 acc[2][2];
    #pragma unroll
    for (int m = 0; m < 2; ++m)
        #pragma unroll
        for (int n = 0; n < 2; ++n) acc[m][n] = zero;

    #define STAGE(buf, k0) { \
        _Pragma("unroll") \
        for (int it = 0; it < 2; ++it) { \
            int s = tid + it*256; \
            int r = s >> 3, g = s & 7; \
            int ksw = (k0) + ((g ^ (r & 7)) << 3); \
            aload16(&As8[buf][s], A  + (size_t)(bm0 + r)*K + ksw); \
            aload16(&Bs8[buf][s], BT + (size_t)(bn0 + r)*K + ksw); \
        } }

    STAGE(0, 0)
    if (NT > 1) STAGE(1, 64)

    #pragma unroll
    for (int t = 0; t < NT; ++t) {
        if (t + 1 < NT) asm volatile("s_waitcnt vmcnt(4)" ::: "memory");
        else            asm volatile("s_waitcnt vmcnt(0)" ::: "memory");
        __builtin_amdgcn_s_barrier();
        __builtin_amdgcn_sched_barrier(0);
        int buf = t % 3;
        sh8 af[2][2], bfv[2][2];
        #pragma unroll
        for (int m = 0; m < 2; ++m) {
            int R = wr*32 + m*16 + lr;
            #pragma unroll
            for (int s = 0; s < 2; ++s) af[m][s] = As8[buf][R*8 + ((s*4+lg) ^ (R & 7))];
        }
        #pragma unroll
        for (int n = 0; n < 2; ++n) {
            int R = wc*32 + n*16 + lr;
            #pragma unroll
            for (int s = 0; s < 2; ++s) bfv[n][s] = Bs8[buf][R*8 + ((s*4+lg) ^ (R & 7))];
        }
        if (t + 2 < NT) STAGE((t+2)%3, (t+2)*64)
        #pragma unroll
        for (int m = 0; m < 2; ++m)
            #pragma unroll
            for (int n = 0; n < 2; ++n)
                #pragma unroll
                for (int s = 0; s < 2; ++s)
                    acc[m][n] = mfma16(af[m][s], bfv[n][s], acc[m][n]);
        asm volatile("s_waitcnt lgkmcnt(0)" ::: "memory");
    }
    #undef STAGE

    if (VTOUT && bn0 >= 1024) {
        __syncthreads();
        short* tb = (short*)&As8[0][0];   // 64 x 68 shorts
        #pragma unroll
        for (int m = 0; m < 2; ++m)
            #pragma unroll
            for (int n = 0; n < 2; ++n)
                #pragma unroll
                for (int r = 0; r < 4; ++r) {
                    int row = wr*32 + m*16 + lg*4 + r;
                    int col = wc*32 + n*16 + lr;
                    float v = acc[m][n][r] + bias[bn0 + col];
                    tb[col*68 + row] = f2bf(v);
                }
        __syncthreads();
        int vd = tid >> 2, t0 = (tid & 3) << 4;
        #pragma unroll
        for (int i = 0; i < 4; ++i) {
            short4 s4 = *reinterpret_cast<short4*>(&tb[vd*68 + t0 + i*4]);
            *reinterpret_cast<short4*>(&vtx[(size_t)(bn0 - 1024 + vd)*2048 + bm0 + t0 + i*4]) = s4;
        }
        return;
    }

    #pragma unroll
    for (int m = 0; m < 2; ++m) {
        #pragma unroll
        for (int n = 0; n < 2; ++n) {
            #pragma unroll
            for (int r = 0; r < 4; ++r) {
                int row = bm0 + wr*32 + m*16 + lg*4 + r;
                int col = bn0 + wc*32 + n*16 + lr;
                float v = acc[m][n][r] + (BIAS_ROW ? bias[row] : bias[col]);
                if (QSC && col < 512) v *= (0.125f * LOG2E);
                if (EPI == 1) v += res[(size_t)row*ldc + col];
                if (EPI == 2) v = 0.5f * v * (1.0f + erff(v * 0.70710678f));
                if (OUTBF) ((short*)Cout)[(size_t)row*ldc + col] = f2bf(v);
                else       ((float*)Cout)[(size_t)row*ldc + col] = v;
            }
        }
    }
}

// ---------------- bf16 MFMA GEMM, 64x32 tile ----------------
template<int EPI, bool OUTBF, bool BIAS_ROW, int NT>
__global__ __launch_bounds__(256) void gemm32n(
    const short* __restrict__ A, const short* __restrict__ BT,
    const float* __restrict__ bias, const float* __restrict__ res,
    void* __restrict__ Cout, int M, int N, int K, int nbx)
{
    __shared__ sh8 As8[3][512];
    __shared__ sh8 Bs8[3][256];
    int tid = threadIdx.x;
    int w = tid >> 6, lane = tid & 63, lr = lane & 15, lg = lane >> 4;
    int cpx = gridDim.x >> 3;
    int swz = (blockIdx.x & 7)*cpx + (blockIdx.x >> 3);
    int bx = swz % nbx, by = swz / nbx;
    int bm0 = by*64, bn0 = bx*32;

    f32x4 zero = {0.f,0.f,0.f,0.f};
    f32x4 acc[2];
    acc[0] = zero; acc[1] = zero;

    #define STAGE32(buf, k0) { \
        _Pragma("unroll") \
        for (int it = 0; it < 2; ++it) { \
            int s = tid + it*256; \
            int r = s >> 3, g = s & 7; \
            int ksw = (k0) + ((g ^ (r & 7)) << 3); \
            aload16(&As8[buf][s], A + (size_t)(bm0 + r)*K + ksw); \
        } \
        { int r = tid >> 3, g = tid & 7; \
          int ksw = (k0) + ((g ^ (r & 7)) << 3); \
          aload16(&Bs8[buf][tid], BT + (size_t)(bn0 + r)*K + ksw); } }

    STAGE32(0, 0)
    if (NT > 1) STAGE32(1, 64)

    #pragma unroll
    for (int t = 0; t < NT; ++t) {
        if (t + 1 < NT) asm volatile("s_waitcnt vmcnt(3)" ::: "memory");
        else            asm volatile("s_waitcnt vmcnt(0)" ::: "memory");
        __builtin_amdgcn_s_barrier();
        __builtin_amdgcn_sched_barrier(0);
        int buf = t % 3;
        sh8 af[2], bfv[2][2];
        int Ra = w*16 + lr;
        #pragma unroll
        for (int s = 0; s < 2; ++s) af[s] = As8[buf][Ra*8 + ((s*4+lg) ^ (Ra & 7))];
        #pragma unroll
        for (int n = 0; n < 2; ++n) {
            int R = n*16 + lr;
            #pragma unroll
            for (int s = 0; s < 2; ++s) bfv[n][s] = Bs8[buf][R*8 + ((s*4+lg) ^ (R & 7))];
        }
        if (t + 2 < NT) STAGE32((t+2)%3, (t+2)*64)
        #pragma unroll
        for (int n = 0; n < 2; ++n)
            #pragma unroll
            for (int s = 0; s < 2; ++s)
                acc[n] = mfma16(af[s], bfv[n][s], acc[n]);
        asm volatile("s_waitcnt lgkmcnt(0)" ::: "memory");
    }
    #undef STAGE32

    #pragma unroll
    for (int n = 0; n < 2; ++n) {
        #pragma unroll
        for (int r = 0; r < 4; ++r) {
            int row = bm0 + w*16 + lg*4 + r;
            int col = bn0 + n*16 + lr;
            float v = acc[n][r] + (BIAS_ROW ? bias[row] : bias[col]);
            if (EPI == 1) v += res[(size_t)row*N + col];
            if (EPI == 2) v = 0.5f * v * (1.0f + erff(v * 0.70710678f));
            if (OUTBF) ((short*)Cout)[(size_t)row*N + col] = f2bf(v);
            else       ((float*)Cout)[(size_t)row*N + col] = v;
        }
    }
}

// ---------------- MFMA flash attention: ALL 4 KV tiles staged upfront ---------
__global__ __launch_bounds__(512) void attn_reg(
    const short* __restrict__ qk, const short* __restrict__ vt,
    const short* __restrict__ rnP, const unsigned long long* __restrict__ mbP,
    const float* __restrict__ w_edge, short* __restrict__ OpA,
    short* __restrict__ OpB, float* __restrict__ ml)
{
    __shared__ sh8 Ks8[4][512];   // 32 KB
    __shared__ sh8 Vs8[4][512];   // 32 KB

    int cpx = gridDim.x >> 3;     // 64
    int swz = (blockIdx.x & 7)*cpx + (blockIdx.x >> 3);
    int w = threadIdx.x >> 6, lane = threadIdx.x & 63;
    int lr = lane & 15, lg = lane >> 4;
    int qb = swz & 7;
    int h  = (swz >> 3) & 7;
    int b  = (swz >> 6) & 1;
    int ks = swz >> 7;

    const int q0 = qb*128 + w*16;
    const int qrow0 = b*NTOK + q0;
    const int jt0 = ks*4;
    const int bqt = b*64 + qb*8 + w;

    sh8 qf[2];
    #pragma unroll
    for (int s = 0; s < 2; ++s)
        qf[s] = *reinterpret_cast<const sh8*>(qk + (size_t)(qrow0 + lr)*1024 + h*64 + s*32 + lg*8);

    float we2l = w_edge[2*NHEADS + h] * LOG2E;

    float m_i = -1e30f, l_lane = 0.f;
    f32x4 zero = {0.f,0.f,0.f,0.f};
    f32x4 accO[4];
    #pragma unroll
    for (int n = 0; n < 4; ++n) accO[n] = zero;

    const short* kbase = qk + 512 + h*64;
    const short* vbase = vt + (size_t)h*64*2048 + b*NTOK;
    int sr = threadIdx.x >> 3, sg = threadIdx.x & 7;
    int sx = (sg ^ (sr & 7)) << 3;

    #pragma unroll
    for (int t = 0; t < 4; ++t) {
        aload16(&Ks8[t][threadIdx.x], kbase + (size_t)(b*NTOK + (jt0 + t)*64 + sr)*1024 + sx);
        aload16(&Vs8[t][threadIdx.x], vbase + (size_t)sr*2048 + (jt0 + t)*64 + sx);
    }
    short4 rn_reg[4][4];
    unsigned long long mr_reg[4];
    #pragma unroll
    for (int t = 0; t < 4; ++t) {
        #pragma unroll
        for (int n = 0; n < 4; ++n)
            rn_reg[t][n] = *reinterpret_cast<const short4*>(
                &rnP[(size_t)(((bqt*16 + jt0 + t)*4 + n)*256) + lane*4]);
        mr_reg[t] = mbP[(size_t)(bqt*16 + jt0 + t)*16 + lr];
    }

    asm volatile("s_waitcnt vmcnt(0)" ::: "memory");
    __builtin_amdgcn_s_barrier();

    #pragma unroll
    for (int t = 0; t < 4; ++t) {
        f32x4 Sv[4];
        #pragma unroll
        for (int n = 0; n < 4; ++n) {
            int kcol = n*16 + lr;
            sh8 k0v = Ks8[t][kcol*8 + (lg       ^ (kcol & 7))];
            sh8 k1v = Ks8[t][kcol*8 + ((4 + lg) ^ (kcol & 7))];
            Sv[n] = mfma16(k1v, qf[1], mfma16(k0v, qf[0], zero));
        }

        #pragma unroll
        for (int n = 0; n < 4; ++n) {
            short4 rn4 = rn_reg[t][n];
            Sv[n][0] = fmaf(bf2f(rn4.x), we2l, Sv[n][0]);
            Sv[n][1] = fmaf(bf2f(rn4.y), we2l, Sv[n][1]);
            Sv[n][2] = fmaf(bf2f(rn4.z), we2l, Sv[n][2]);
            Sv[n][3] = fmaf(bf2f(rn4.w), we2l, Sv[n][3]);
        }

        float mx = Sv[0][0];
        #pragma unroll
        for (int n = 0; n < 4; ++n)
            #pragma unroll
            for (int r = 0; r < 4; ++r) mx = fmaxf(mx, Sv[n][r]);
        mx = fmaxf(mx, __shfl_xor(mx, 16));
        mx = fmaxf(mx, __shfl_xor(mx, 32));

        if (!__all(mx <= m_i + 8.0f)) {
            float mnew = fmaxf(m_i, mx);
            float f = ex2(m_i - mnew);
            m_i = mnew;
            l_lane *= f;
            float fb[4];
            #pragma unroll
            for (int r = 0; r < 4; ++r) fb[r] = __shfl(f, lg*4 + r);
            #pragma unroll
            for (int n = 0; n < 4; ++n)
                #pragma unroll
                for (int r = 0; r < 4; ++r) accO[n][r] *= fb[r];
        }

        unsigned long long mr = mr_reg[t];
        float ps = 0.f;
        unsigned pk[8];
        #pragma unroll
        for (int n = 0; n < 4; ++n) {
            float p_[4];
            #pragma unroll
            for (int r = 0; r < 4; ++r) {
                float p = ex2(Sv[n][r] - m_i);
                p = ((mr >> (n*16 + lg*4 + r)) & 1ull) ? 0.f : p;
                ps += p;
                p_[r] = p;
            }
            asm("v_cvt_pk_bf16_f32 %0, %1, %2" : "=v"(pk[2*n])   : "v"(p_[0]), "v"(p_[1]));
            asm("v_cvt_pk_bf16_f32 %0, %1, %2" : "=v"(pk[2*n+1]) : "v"(p_[2]), "v"(p_[3]));
        }
        l_lane += ps;

        int src0 = lr + ((lg & 1) << 5);
        int src1 = src0 + 16;
        sh8 pa[2];
        #pragma unroll
        for (int s = 0; s < 2; ++s) {
            int ns = 2*s + (lg >> 1);
            u32x4 dv;
            dv.x = (unsigned)__shfl((int)pk[2*ns],   src0);
            dv.y = (unsigned)__shfl((int)pk[2*ns+1], src0);
            dv.z = (unsigned)__shfl((int)pk[2*ns],   src1);
            dv.w = (unsigned)__shfl((int)pk[2*ns+1], src1);
            pa[s] = __builtin_bit_cast(sh8, dv);
        }

        #pragma unroll
        for (int n = 0; n < 4; ++n) {
            int dcol = n*16 + lr;
            sh8 v0 = Vs8[t][dcol*8 + (lg       ^ (dcol & 7))];
            sh8 v1 = Vs8[t][dcol*8 + ((4 + lg) ^ (dcol & 7))];
            accO[n] = mfma16(pa[1], v1, mfma16(pa[0], v0, accO[n]));
        }
    }

    l_lane += __shfl_xor(l_lane, 16);
    l_lane += __shfl_xor(l_lane, 32);

    short* Op = (ks < 2) ? OpA : OpB;
    #pragma unroll
    for (int r = 0; r < 4; ++r) {
        size_t row = (size_t)((ks & 1)*MTOK + qrow0 + lg*4 + r);
        #pragma unroll
        for (int n = 0; n < 4; ++n)
            Op[row*512 + h*64 + n*16 + lr] = f2bf(accO[n][r]);
    }
    if (lg == 0) {
        size_t mrow = (size_t)(ks*MTOK + qrow0 + lr);
        ml[(mrow*NHEADS + h)*2 + 0] = m_i;
        ml[(mrow*NHEADS + h)*2 + 1] = l_lane;
    }
}

// ---------------- combine 4 KV-split partials -> bf16 O ----------------
__global__ __launch_bounds__(256) void attn_combine4(const short* __restrict__ OpA,
    const short* __restrict__ OpB, const float* __restrict__ ml,
    short* __restrict__ ob)
{
    int idx = blockIdx.x*256 + threadIdx.x;
    int tok = idx >> 7, dd = (idx & 127) * 4;
    int h = dd >> 6;
    float m[4], l[4];
    #pragma unroll
    for (int s = 0; s < 4; ++s) {
        m[s] = ml[(((size_t)s*MTOK + tok)*NHEADS + h)*2 + 0];
        l[s] = ml[(((size_t)s*MTOK + tok)*NHEADS + h)*2 + 1];
    }
    float mm = fmaxf(fmaxf(m[0], m[1]), fmaxf(m[2], m[3]));
    float wsum = 0.f, a0 = 0.f, a1 = 0.f, a2 = 0.f, a3 = 0.f;
    #pragma unroll
    for (int s = 0; s < 4; ++s) {
        float wv = ex2(m[s] - mm);
        wsum += wv * l[s];
        const short* Op = (s < 2) ? OpA : OpB;
        short4 p = *reinterpret_cast<const short4*>(&Op[((size_t)((s&1)*MTOK) + tok)*512 + dd]);
        a0 += bf2f(p.x)*wv; a1 += bf2f(p.y)*wv;
        a2 += bf2f(p.z)*wv; a3 += bf2f(p.w)*wv;
    }
    float inv = 1.f / wsum;
    short4 o;
    o.x = f2bf(a0*inv); o.y = f2bf(a1*inv);
    o.z = f2bf(a2*inv); o.w = f2bf(a3*inv);
    *reinterpret_cast<short4*>(&ob[(size_t)tok*512 + dd]) = o;
}

// -------------------------------------------------------------------------------
extern "C" void kernel_launch(void* const* d_in, const int* in_sizes, int n_in,
                              void* d_out, int out_size, void* d_ws, size_t ws_size,
                              hipStream_t stream)
{
    const float* x      = (const float*)d_in[0];
    const float* coords = (const float*)d_in[1];
    const unsigned char* mask = (const unsigned char*)d_in[2];
    const float* ln1_g = (const float*)d_in[3];
    const float* ln1_b = (const float*)d_in[4];
    const float* w_qkv = (const float*)d_in[5];
    const float* b_qkv = (const float*)d_in[6];
    const float* w_edge= (const float*)d_in[7];
    const float* w_out = (const float*)d_in[8];
    const float* b_out = (const float*)d_in[9];
    const float* ln2_g = (const float*)d_in[10];
    const float* ln2_b = (const float*)d_in[11];
    const float* w1    = (const float*)d_in[12];
    const float* b1    = (const float*)d_in[13];
    const float* w2    = (const float*)d_in[14];
    const float* b2    = (const float*)d_in[15];
    float* out = (float*)d_out;

    char* W = (char*)d_ws;
    const size_t MB = 1024*1024;
    float* x1    = (float*)(W);                    // [0,4M)
    short* qk    = (short*)(W + 4*MB);             // [4M,8M)
    short* vtb   = (short*)(W + 8*MB);             // [8M,10M)
    short* woutT = (short*)(W + 10*MB);            // [10M,10.5M)
    short* xln   = (short*)(W + 10*MB + 512*1024); // [10.5M,12.5M)  (later y)
    short* wqkvT = (short*)(W + 12*MB + 512*1024); // [12.5M,14M)
    short* OpB   = (short*)(W + 10*MB + 512*1024); // [10.5M,14.5M) (xln dead then)
    short* OpA   = (short*)(W + 14*MB + 512*1024); // [14.5M,18.5M)
    short* rnP   = (short*)(W + 18*MB + 512*1024); // [18.5M,22.5M)
    float* mlp   = (float*)(W + 22*MB + 512*1024); // [22.5M,23M)
    unsigned long long* mbP = (unsigned long long*)(W + 23*MB); // [23M,23.25M)
    short* ob    = (short*)(W + 6*MB);             // [6M,8M)
    short* y     = xln;
    short* w1T   = (short*)(W + 23*MB + 256*1024); // [23.25M,25.25M)
    short* w2T   = (short*)(W + 25*MB + 256*1024); // [25.25M,27.25M)
    short* hid   = (short*)(W + 14*MB + 512*1024); // [14.5M,22.5M) (OpA/rnP dead)

    // ---- front: prep + ALL weight transposes + LN1, one mega-kernel ----
    front<<<dim3(7168,1,1), 256, 0, stream>>>(coords, mask, rnP, mbP,
        w_qkv, wqkvT, w_out, woutT, w1, w1T, w2, w2T, x, ln1_g, ln1_b, xln);
    // fused QKV + V^T
    gemm64<0,true,false,true,8,true><<<dim3(768,1,1), 256, 0, stream>>>(
        xln, wqkvT, b_qkv, nullptr, qk, vtb, MTOK, 1536, 512, 24, 1024);
    attn_reg<<<dim3(512,1,1), 512, 0, stream>>>(qk, vtb, rnP, mbP, w_edge, OpA, OpB, mlp);
    attn_combine4<<<dim3(1024,1,1), 256, 0, stream>>>(OpA, OpB, mlp, ob);
    // x1 = ob @ w_out + b_out + x
    gemm32n<1,false,false,8><<<dim3(512,1,1), 256, 0, stream>>>(
        ob, woutT, b_out, x, x1, MTOK, 512, 512, 16);
    // ---- phase 2 ----
    ln_bf16<<<MTOK, 256, 0, stream>>>(x1, ln2_g, ln2_b, y);
    gemm64<2,true,false,false,8,false><<<dim3(1024,1,1), 256, 0, stream>>>(
        y, w1T, b1, nullptr, hid, nullptr, MTOK, 2048, 512, 32, 2048);
    // out = hid @ w2 + b2 + x1
    gemm32n<1,false,false,32><<<dim3(512,1,1), 256, 0, stream>>>(
        hid, w2T, b2, x1, out, MTOK, 512, 2048, 16);
}

// Round 19
// 78.765 us; speedup vs baseline: 2.1216x; 1.0082x over previous
//
#include <hip/hip_runtime.h>
#include <hip/hip_bf16.h>
#include <math.h>

#define NHEADS 8
#define NTOK   1024
#define MTOK   2048

typedef __attribute__((ext_vector_type(8))) short  sh8;
typedef __attribute__((ext_vector_type(8))) __bf16 bf16x8;
typedef __attribute__((ext_vector_type(4))) float  f32x4;
typedef __attribute__((ext_vector_type(4))) unsigned int u32x4;

__device__ __forceinline__ short f2bf(float v) {
    return __builtin_bit_cast(short, __float2bfloat16(v));
}
__device__ __forceinline__ float bf2f(short v) {
    return __builtin_bit_cast(float, ((unsigned)(unsigned short)v) << 16);
}
__device__ __forceinline__ float ex2(float v) {
    return __builtin_amdgcn_exp2f(v);
}
__device__ __forceinline__ f32x4 mfma16(sh8 a, sh8 b, f32x4 c) {
    return __builtin_amdgcn_mfma_f32_16x16x32_bf16(
        __builtin_bit_cast(bf16x8, a), __builtin_bit_cast(bf16x8, b), c, 0, 0, 0);
}
__device__ __forceinline__ void aload16(void* lds, const void* g) {
    __builtin_amdgcn_global_load_lds(
        (const __attribute__((address_space(1))) unsigned int*)g,
        (__attribute__((address_space(3))) unsigned int*)lds, 16, 0, 0);
}

#define LOG2E 1.4426950408889634f

// ---------------- LayerNorm row body ----------------
__device__ __forceinline__ void ln_row(const float* __restrict__ x,
    const float* __restrict__ g, const float* __restrict__ bta,
    short* __restrict__ y, int row, int t)
{
    const float* xr = x + (size_t)row * 512;
    float2 v = *reinterpret_cast<const float2*>(&xr[t*2]);
    float s = v.x + v.y, ss = v.x*v.x + v.y*v.y;
    #pragma unroll
    for (int m = 1; m < 64; m <<= 1) { s += __shfl_xor(s, m); ss += __shfl_xor(ss, m); }
    __shared__ float red[8];
    int wid = t >> 6, lane = t & 63;
    if (!lane) { red[wid] = s; red[4+wid] = ss; }
    __syncthreads();
    s = red[0]+red[1]+red[2]+red[3]; ss = red[4]+red[5]+red[6]+red[7];
    float mu = s*(1.f/512), var = ss*(1.f/512) - mu*mu, rs = rsqrtf(var + 1e-5f);
    float2 gg = *reinterpret_cast<const float2*>(&g[t*2]);
    float2 bb = *reinterpret_cast<const float2*>(&bta[t*2]);
    short2 o; o.x = f2bf((v.x-mu)*rs*gg.x + bb.x); o.y = f2bf((v.y-mu)*rs*gg.y + bb.y);
    *reinterpret_cast<short2*>(&y[(size_t)row*512 + t*2]) = o;
}

__global__ __launch_bounds__(256) void ln_bf16(const float* __restrict__ x,
    const float* __restrict__ g, const float* __restrict__ bta, short* __restrict__ y)
{
    ln_row(x, g, bta, y, blockIdx.x, threadIdx.x);
}

// ---------------- weight transpose body: W[K][N] f32 -> WT[N][K] bf16 ----------
__device__ __forceinline__ void wconv_body(const float* __restrict__ W,
    short* __restrict__ WT, int K, int N, int bid)
{
    int nbx = N >> 5;
    int bn = (bid % nbx) * 32, bk = (bid / nbx) * 32;
    __shared__ float t[32][33];
    int c = threadIdx.x & 31, r8 = threadIdx.x >> 5;
    #pragma unroll
    for (int i = 0; i < 4; ++i) {
        int r = r8 + i*8;
        t[r][c] = W[(size_t)(bk + r)*N + bn + c];
    }
    __syncthreads();
    #pragma unroll
    for (int i = 0; i < 4; ++i) {
        int r = r8 + i*8;
        WT[(size_t)(bn + r)*K + bk + c] = f2bf(t[c][r]);
    }
}

// ---------------- FRONT mega-kernel: prep + all weight transposes + LN1 --------
__global__ __launch_bounds__(256) void front(
    const float* __restrict__ coords, const unsigned char* __restrict__ mask,
    short* __restrict__ rnP, unsigned long long* __restrict__ mbP,
    const float* __restrict__ w_qkv, short* __restrict__ wqkvT,
    const float* __restrict__ w_out, short* __restrict__ woutT,
    const float* __restrict__ w1, short* __restrict__ w1T,
    const float* __restrict__ w2, short* __restrict__ w2T,
    const float* __restrict__ x, const float* __restrict__ ln1_g,
    const float* __restrict__ ln1_b, short* __restrict__ xln)
{
    int bid = blockIdx.x;
    if (bid >= 5120) { ln_row(x, ln1_g, ln1_b, xln, bid - 5120, threadIdx.x); return; }
    if (bid >= 4096) { wconv_body(w2, w2T, 2048, 512, bid - 4096); return; }
    if (bid >= 3072) { wconv_body(w1, w1T, 512, 2048, bid - 3072); return; }
    if (bid >= 2048) {
        int b2 = bid - 2048;
        if (b2 < 768) wconv_body(w_qkv, wqkvT, 512, 1536, b2);
        else          wconv_body(w_out, woutT, 512, 512, b2 - 768);
        return;
    }
    __shared__ float2 kc_s[64];
    __shared__ float2 qc_s[16];
    int bqt = bid >> 4, jt = bid & 15;
    int b = bqt >> 6, qt = bqt & 63;
    int t = threadIdx.x, w = t >> 6, lane = t & 63;
    int lr = lane & 15, lg = lane >> 4;

    if (t < 64)       kc_s[t]      = *reinterpret_cast<const float2*>(&coords[(size_t)(b*1024 + jt*64 + t)*2]);
    else if (t < 80)  qc_s[t - 64] = *reinterpret_cast<const float2*>(&coords[(size_t)(b*1024 + qt*16 + (t - 64))*2]);
    __syncthreads();

    float2 qc = qc_s[lr];
    short4 o;
    short* op = &o.x;
    #pragma unroll
    for (int r = 0; r < 4; ++r) {
        float2 kc = kc_s[w*16 + lg*4 + r];
        float dx = qc.x - kc.x, dy = qc.y - kc.y;
        op[r] = f2bf(sqrtf(dx*dx + dy*dy));
    }
    *reinterpret_cast<short4*>(&rnP[(size_t)((bid*4 + w)*256) + lane*4]) = o;

    #pragma unroll
    for (int i = 0; i < 4; ++i) {
        int q = w*4 + i;
        unsigned char v = mask[(size_t)(b*1024 + qt*16 + q)*NTOK + jt*64 + lane];
        unsigned long long bits = __ballot(v != 0);
        if (!lane) mbP[(size_t)bid*16 + q] = bits;
    }
}

// ---------------- bf16 MFMA GEMM, 64x64 tile, BK=64, 3-stage counted-vmcnt ----
template<int EPI, bool OUTBF, bool BIAS_ROW, bool QSC, int NT, bool VTOUT>
__global__ __launch_bounds__(256) void gemm64(
    const short* __restrict__ A, const short* __restrict__ BT,
    const float* __restrict__ bias, const float* __restrict__ res,
    void* __restrict__ Cout, short* __restrict__ vtx,
    int M, int N, int K, int nbx, int ldc)
{
    __shared__ sh8 As8[3][512];
    __shared__ sh8 Bs8[3][512];
    int tid = threadIdx.x;
    int w = tid >> 6, lane = tid & 63, lr = lane & 15, lg = lane >> 4;
    int wr = w >> 1, wc = w & 1;
    int cpx = gridDim.x >> 3;
    int swz = (blockIdx.x & 7)*cpx + (blockIdx.x >> 3);
    int bx = swz % nbx, by = swz / nbx;
    int bm0 = by*64, bn0 = bx*64;

    f32x4 zero = {0.f,0.f,0.f,0.f};
    f32x4 acc[2][2];
    #pragma unroll
    for (int m = 0; m < 2; ++m)
        #pragma unroll
        for (int n = 0; n < 2; ++n) acc[m][n] = zero;

    #define STAGE(buf, k0) { \
        _Pragma("unroll") \
        for (int it = 0; it < 2; ++it) { \
            int s = tid + it*256; \
            int r = s >> 3, g = s & 7; \
            int ksw = (k0) + ((g ^ (r & 7)) << 3); \
            aload16(&As8[buf][s], A  + (size_t)(bm0 + r)*K + ksw); \
            aload16(&Bs8[buf][s], BT + (size_t)(bn0 + r)*K + ksw); \
        } }

    STAGE(0, 0)
    if (NT > 1) STAGE(1, 64)

    #pragma unroll
    for (int t = 0; t < NT; ++t) {
        if (t + 1 < NT) asm volatile("s_waitcnt vmcnt(4)" ::: "memory");
        else            asm volatile("s_waitcnt vmcnt(0)" ::: "memory");
        __builtin_amdgcn_s_barrier();
        __builtin_amdgcn_sched_barrier(0);
        int buf = t % 3;
        sh8 af[2][2], bfv[2][2];
        #pragma unroll
        for (int m = 0; m < 2; ++m) {
            int R = wr*32 + m*16 + lr;
            #pragma unroll
            for (int s = 0; s < 2; ++s) af[m][s] = As8[buf][R*8 + ((s*4+lg) ^ (R & 7))];
        }
        #pragma unroll
        for (int n = 0; n < 2; ++n) {
            int R = wc*32 + n*16 + lr;
            #pragma unroll
            for (int s = 0; s < 2; ++s) bfv[n][s] = Bs8[buf][R*8 + ((s*4+lg) ^ (R & 7))];
        }
        if (t + 2 < NT) STAGE((t+2)%3, (t+2)*64)
        #pragma unroll
        for (int m = 0; m < 2; ++m)
            #pragma unroll
            for (int n = 0; n < 2; ++n)
                #pragma unroll
                for (int s = 0; s < 2; ++s)
                    acc[m][n] = mfma16(af[m][s], bfv[n][s], acc[m][n]);
        asm volatile("s_waitcnt lgkmcnt(0)" ::: "memory");
    }
    #undef STAGE

    if (VTOUT && bn0 >= 1024) {
        __syncthreads();
        short* tb = (short*)&As8[0][0];   // 64 x 68 shorts
        #pragma unroll
        for (int m = 0; m < 2; ++m)
            #pragma unroll
            for (int n = 0; n < 2; ++n)
                #pragma unroll
                for (int r = 0; r < 4; ++r) {
                    int row = wr*32 + m*16 + lg*4 + r;
                    int col = wc*32 + n*16 + lr;
                    float v = acc[m][n][r] + bias[bn0 + col];
                    tb[col*68 + row] = f2bf(v);
                }
        __syncthreads();
        int vd = tid >> 2, t0 = (tid & 3) << 4;
        #pragma unroll
        for (int i = 0; i < 4; ++i) {
            short4 s4 = *reinterpret_cast<short4*>(&tb[vd*68 + t0 + i*4]);
            *reinterpret_cast<short4*>(&vtx[(size_t)(bn0 - 1024 + vd)*2048 + bm0 + t0 + i*4]) = s4;
        }
        return;
    }

    #pragma unroll
    for (int m = 0; m < 2; ++m) {
        #pragma unroll
        for (int n = 0; n < 2; ++n) {
            #pragma unroll
            for (int r = 0; r < 4; ++r) {
                int row = bm0 + wr*32 + m*16 + lg*4 + r;
                int col = bn0 + wc*32 + n*16 + lr;
                float v = acc[m][n][r] + (BIAS_ROW ? bias[row] : bias[col]);
                if (QSC && col < 512) v *= (0.125f * LOG2E);
                if (EPI == 1) v += res[(size_t)row*ldc + col];
                if (EPI == 2) v = 0.5f * v * (1.0f + erff(v * 0.70710678f));
                if (OUTBF) ((short*)Cout)[(size_t)row*ldc + col] = f2bf(v);
                else       ((float*)Cout)[(size_t)row*ldc + col] = v;
            }
        }
    }
}

// ---------------- bf16 MFMA GEMM, 64x32 tile ----------------
template<int EPI, bool OUTBF, bool BIAS_ROW, int NT>
__global__ __launch_bounds__(256) void gemm32n(
    const short* __restrict__ A, const short* __restrict__ BT,
    const float* __restrict__ bias, const float* __restrict__ res,
    void* __restrict__ Cout, int M, int N, int K, int nbx)
{
    __shared__ sh8 As8[3][512];
    __shared__ sh8 Bs8[3][256];
    int tid = threadIdx.x;
    int w = tid >> 6, lane = tid & 63, lr = lane & 15, lg = lane >> 4;
    int cpx = gridDim.x >> 3;
    int swz = (blockIdx.x & 7)*cpx + (blockIdx.x >> 3);
    int bx = swz % nbx, by = swz / nbx;
    int bm0 = by*64, bn0 = bx*32;

    f32x4 zero = {0.f,0.f,0.f,0.f};
    f32x4 acc[2];
    acc[0] = zero; acc[1] = zero;

    #define STAGE32(buf, k0) { \
        _Pragma("unroll") \
        for (int it = 0; it < 2; ++it) { \
            int s = tid + it*256; \
            int r = s >> 3, g = s & 7; \
            int ksw = (k0) + ((g ^ (r & 7)) << 3); \
            aload16(&As8[buf][s], A + (size_t)(bm0 + r)*K + ksw); \
        } \
        { int r = tid >> 3, g = tid & 7; \
          int ksw = (k0) + ((g ^ (r & 7)) << 3); \
          aload16(&Bs8[buf][tid], BT + (size_t)(bn0 + r)*K + ksw); } }

    STAGE32(0, 0)
    if (NT > 1) STAGE32(1, 64)

    #pragma unroll
    for (int t = 0; t < NT; ++t) {
        if (t + 1 < NT) asm volatile("s_waitcnt vmcnt(3)" ::: "memory");
        else            asm volatile("s_waitcnt vmcnt(0)" ::: "memory");
        __builtin_amdgcn_s_barrier();
        __builtin_amdgcn_sched_barrier(0);
        int buf = t % 3;
        sh8 af[2], bfv[2][2];
        int Ra = w*16 + lr;
        #pragma unroll
        for (int s = 0; s < 2; ++s) af[s] = As8[buf][Ra*8 + ((s*4+lg) ^ (Ra & 7))];
        #pragma unroll
        for (int n = 0; n < 2; ++n) {
            int R = n*16 + lr;
            #pragma unroll
            for (int s = 0; s < 2; ++s) bfv[n][s] = Bs8[buf][R*8 + ((s*4+lg) ^ (R & 7))];
        }
        if (t + 2 < NT) STAGE32((t+2)%3, (t+2)*64)
        #pragma unroll
        for (int n = 0; n < 2; ++n)
            #pragma unroll
            for (int s = 0; s < 2; ++s)
                acc[n] = mfma16(af[s], bfv[n][s], acc[n]);
        asm volatile("s_waitcnt lgkmcnt(0)" ::: "memory");
    }
    #undef STAGE32

    #pragma unroll
    for (int n = 0; n < 2; ++n) {
        #pragma unroll
        for (int r = 0; r < 4; ++r) {
            int row = bm0 + w*16 + lg*4 + r;
            int col = bn0 + n*16 + lr;
            float v = acc[n][r] + (BIAS_ROW ? bias[row] : bias[col]);
            if (EPI == 1) v += res[(size_t)row*N + col];
            if (EPI == 2) v = 0.5f * v * (1.0f + erff(v * 0.70710678f));
            if (OUTBF) ((short*)Cout)[(size_t)row*N + col] = f2bf(v);
            else       ((float*)Cout)[(size_t)row*N + col] = v;
        }
    }
}

// ---------------- MFMA flash attention: ALL 4 KV tiles staged upfront ---------
// + s_setprio around MFMA clusters (waves at independent phases post-barrier)
__global__ __launch_bounds__(512) void attn_reg(
    const short* __restrict__ qk, const short* __restrict__ vt,
    const short* __restrict__ rnP, const unsigned long long* __restrict__ mbP,
    const float* __restrict__ w_edge, short* __restrict__ OpA,
    short* __restrict__ OpB, float* __restrict__ ml)
{
    __shared__ sh8 Ks8[4][512];   // 32 KB
    __shared__ sh8 Vs8[4][512];   // 32 KB

    int cpx = gridDim.x >> 3;     // 64
    int swz = (blockIdx.x & 7)*cpx + (blockIdx.x >> 3);
    int w = threadIdx.x >> 6, lane = threadIdx.x & 63;
    int lr = lane & 15, lg = lane >> 4;
    int qb = swz & 7;
    int h  = (swz >> 3) & 7;
    int b  = (swz >> 6) & 1;
    int ks = swz >> 7;

    const int q0 = qb*128 + w*16;
    const int qrow0 = b*NTOK + q0;
    const int jt0 = ks*4;
    const int bqt = b*64 + qb*8 + w;

    sh8 qf[2];
    #pragma unroll
    for (int s = 0; s < 2; ++s)
        qf[s] = *reinterpret_cast<const sh8*>(qk + (size_t)(qrow0 + lr)*1024 + h*64 + s*32 + lg*8);

    float we2l = w_edge[2*NHEADS + h] * LOG2E;

    float m_i = -1e30f, l_lane = 0.f;
    f32x4 zero = {0.f,0.f,0.f,0.f};
    f32x4 accO[4];
    #pragma unroll
    for (int n = 0; n < 4; ++n) accO[n] = zero;

    const short* kbase = qk + 512 + h*64;
    const short* vbase = vt + (size_t)h*64*2048 + b*NTOK;
    int sr = threadIdx.x >> 3, sg = threadIdx.x & 7;
    int sx = (sg ^ (sr & 7)) << 3;

    #pragma unroll
    for (int t = 0; t < 4; ++t) {
        aload16(&Ks8[t][threadIdx.x], kbase + (size_t)(b*NTOK + (jt0 + t)*64 + sr)*1024 + sx);
        aload16(&Vs8[t][threadIdx.x], vbase + (size_t)sr*2048 + (jt0 + t)*64 + sx);
    }
    short4 rn_reg[4][4];
    unsigned long long mr_reg[4];
    #pragma unroll
    for (int t = 0; t < 4; ++t) {
        #pragma unroll
        for (int n = 0; n < 4; ++n)
            rn_reg[t][n] = *reinterpret_cast<const short4*>(
                &rnP[(size_t)(((bqt*16 + jt0 + t)*4 + n)*256) + lane*4]);
        mr_reg[t] = mbP[(size_t)(bqt*16 + jt0 + t)*16 + lr];
    }

    asm volatile("s_waitcnt vmcnt(0)" ::: "memory");
    __builtin_amdgcn_s_barrier();

    #pragma unroll
    for (int t = 0; t < 4; ++t) {
        f32x4 Sv[4];
        __builtin_amdgcn_s_setprio(1);
        #pragma unroll
        for (int n = 0; n < 4; ++n) {
            int kcol = n*16 + lr;
            sh8 k0v = Ks8[t][kcol*8 + (lg       ^ (kcol & 7))];
            sh8 k1v = Ks8[t][kcol*8 + ((4 + lg) ^ (kcol & 7))];
            Sv[n] = mfma16(k1v, qf[1], mfma16(k0v, qf[0], zero));
        }
        __builtin_amdgcn_s_setprio(0);

        #pragma unroll
        for (int n = 0; n < 4; ++n) {
            short4 rn4 = rn_reg[t][n];
            Sv[n][0] = fmaf(bf2f(rn4.x), we2l, Sv[n][0]);
            Sv[n][1] = fmaf(bf2f(rn4.y), we2l, Sv[n][1]);
            Sv[n][2] = fmaf(bf2f(rn4.z), we2l, Sv[n][2]);
            Sv[n][3] = fmaf(bf2f(rn4.w), we2l, Sv[n][3]);
        }

        float mx = Sv[0][0];
        #pragma unroll
        for (int n = 0; n < 4; ++n)
            #pragma unroll
            for (int r = 0; r < 4; ++r) mx = fmaxf(mx, Sv[n][r]);
        mx = fmaxf(mx, __shfl_xor(mx, 16));
        mx = fmaxf(mx, __shfl_xor(mx, 32));

        if (!__all(mx <= m_i + 8.0f)) {
            float mnew = fmaxf(m_i, mx);
            float f = ex2(m_i - mnew);
            m_i = mnew;
            l_lane *= f;
            float fb[4];
            #pragma unroll
            for (int r = 0; r < 4; ++r) fb[r] = __shfl(f, lg*4 + r);
            #pragma unroll
            for (int n = 0; n < 4; ++n)
                #pragma unroll
                for (int r = 0; r < 4; ++r) accO[n][r] *= fb[r];
        }

        unsigned long long mr = mr_reg[t];
        float ps = 0.f;
        unsigned pk[8];
        #pragma unroll
        for (int n = 0; n < 4; ++n) {
            float p_[4];
            #pragma unroll
            for (int r = 0; r < 4; ++r) {
                float p = ex2(Sv[n][r] - m_i);
                p = ((mr >> (n*16 + lg*4 + r)) & 1ull) ? 0.f : p;
                ps += p;
                p_[r] = p;
            }
            asm("v_cvt_pk_bf16_f32 %0, %1, %2" : "=v"(pk[2*n])   : "v"(p_[0]), "v"(p_[1]));
            asm("v_cvt_pk_bf16_f32 %0, %1, %2" : "=v"(pk[2*n+1]) : "v"(p_[2]), "v"(p_[3]));
        }
        l_lane += ps;

        int src0 = lr + ((lg & 1) << 5);
        int src1 = src0 + 16;
        sh8 pa[2];
        #pragma unroll
        for (int s = 0; s < 2; ++s) {
            int ns = 2*s + (lg >> 1);
            u32x4 dv;
            dv.x = (unsigned)__shfl((int)pk[2*ns],   src0);
            dv.y = (unsigned)__shfl((int)pk[2*ns+1], src0);
            dv.z = (unsigned)__shfl((int)pk[2*ns],   src1);
            dv.w = (unsigned)__shfl((int)pk[2*ns+1], src1);
            pa[s] = __builtin_bit_cast(sh8, dv);
        }

        __builtin_amdgcn_s_setprio(1);
        #pragma unroll
        for (int n = 0; n < 4; ++n) {
            int dcol = n*16 + lr;
            sh8 v0 = Vs8[t][dcol*8 + (lg       ^ (dcol & 7))];
            sh8 v1 = Vs8[t][dcol*8 + ((4 + lg) ^ (dcol & 7))];
            accO[n] = mfma16(pa[1], v1, mfma16(pa[0], v0, accO[n]));
        }
        __builtin_amdgcn_s_setprio(0);
    }

    l_lane += __shfl_xor(l_lane, 16);
    l_lane += __shfl_xor(l_lane, 32);

    short* Op = (ks < 2) ? OpA : OpB;
    #pragma unroll
    for (int r = 0; r < 4; ++r) {
        size_t row = (size_t)((ks & 1)*MTOK + qrow0 + lg*4 + r);
        #pragma unroll
        for (int n = 0; n < 4; ++n)
            Op[row*512 + h*64 + n*16 + lr] = f2bf(accO[n][r]);
    }
    if (lg == 0) {
        size_t mrow = (size_t)(ks*MTOK + qrow0 + lr);
        ml[(mrow*NHEADS + h)*2 + 0] = m_i;
        ml[(mrow*NHEADS + h)*2 + 1] = l_lane;
    }
}

// ---------------- combine 4 KV-split partials -> bf16 O (short8, 8 elem/thr) --
__global__ __launch_bounds__(256) void attn_combine4(const short* __restrict__ OpA,
    const short* __restrict__ OpB, const float* __restrict__ ml,
    short* __restrict__ ob)
{
    int idx = blockIdx.x*256 + threadIdx.x;     // MTOK*64 threads
    int tok = idx >> 6, dd = (idx & 63) * 8;
    int h = dd >> 6;
    float m[4], l[4];
    #pragma unroll
    for (int s = 0; s < 4; ++s) {
        float2 mlv = *reinterpret_cast<const float2*>(
            &ml[(((size_t)s*MTOK + tok)*NHEADS + h)*2]);
        m[s] = mlv.x; l[s] = mlv.y;
    }
    float mm = fmaxf(fmaxf(m[0], m[1]), fmaxf(m[2], m[3]));
    float wsum = 0.f, a[8] = {};
    #pragma unroll
    for (int s = 0; s < 4; ++s) {
        float wv = ex2(m[s] - mm);
        wsum += wv * l[s];
        const short* Op = (s < 2) ? OpA : OpB;
        sh8 p = *reinterpret_cast<const sh8*>(&Op[((size_t)((s&1)*MTOK) + tok)*512 + dd]);
        #pragma unroll
        for (int j = 0; j < 8; ++j) a[j] = fmaf(bf2f(p[j]), wv, a[j]);
    }
    float inv = 1.f / wsum;
    sh8 o;
    #pragma unroll
    for (int j = 0; j < 8; ++j) o[j] = f2bf(a[j]*inv);
    *reinterpret_cast<sh8*>(&ob[(size_t)tok*512 + dd]) = o;
}

// -------------------------------------------------------------------------------
extern "C" void kernel_launch(void* const* d_in, const int* in_sizes, int n_in,
                              void* d_out, int out_size, void* d_ws, size_t ws_size,
                              hipStream_t stream)
{
    const float* x      = (const float*)d_in[0];
    const float* coords = (const float*)d_in[1];
    const unsigned char* mask = (const unsigned char*)d_in[2];
    const float* ln1_g = (const float*)d_in[3];
    const float* ln1_b = (const float*)d_in[4];
    const float* w_qkv = (const float*)d_in[5];
    const float* b_qkv = (const float*)d_in[6];
    const float* w_edge= (const float*)d_in[7];
    const float* w_out = (const float*)d_in[8];
    const float* b_out = (const float*)d_in[9];
    const float* ln2_g = (const float*)d_in[10];
    const float* ln2_b = (const float*)d_in[11];
    const float* w1    = (const float*)d_in[12];
    const float* b1    = (const float*)d_in[13];
    const float* w2    = (const float*)d_in[14];
    const float* b2    = (const float*)d_in[15];
    float* out = (float*)d_out;

    char* W = (char*)d_ws;
    const size_t MB = 1024*1024;
    float* x1    = (float*)(W);                    // [0,4M)
    short* qk    = (short*)(W + 4*MB);             // [4M,8M)
    short* vtb   = (short*)(W + 8*MB);             // [8M,10M)
    short* woutT = (short*)(W + 10*MB);            // [10M,10.5M)
    short* xln   = (short*)(W + 10*MB + 512*1024); // [10.5M,12.5M)  (later y)
    short* wqkvT = (short*)(W + 12*MB + 512*1024); // [12.5M,14M)
    short* OpB   = (short*)(W + 10*MB + 512*1024); // [10.5M,14.5M) (xln dead then)
    short* OpA   = (short*)(W + 14*MB + 512*1024); // [14.5M,18.5M)
    short* rnP   = (short*)(W + 18*MB + 512*1024); // [18.5M,22.5M)
    float* mlp   = (float*)(W + 22*MB + 512*1024); // [22.5M,23M)
    unsigned long long* mbP = (unsigned long long*)(W + 23*MB); // [23M,23.25M)
    short* ob    = (short*)(W + 6*MB);             // [6M,8M)
    short* y     = xln;
    short* w1T   = (short*)(W + 23*MB + 256*1024); // [23.25M,25.25M)
    short* w2T   = (short*)(W + 25*MB + 256*1024); // [25.25M,27.25M)
    short* hid   = (short*)(W + 14*MB + 512*1024); // [14.5M,22.5M) (OpA/rnP dead)

    // ---- front: prep + ALL weight transposes + LN1 ----
    front<<<dim3(7168,1,1), 256, 0, stream>>>(coords, mask, rnP, mbP,
        w_qkv, wqkvT, w_out, woutT, w1, w1T, w2, w2T, x, ln1_g, ln1_b, xln);
    // fused QKV + V^T
    gemm64<0,true,false,true,8,true><<<dim3(768,1,1), 256, 0, stream>>>(
        xln, wqkvT, b_qkv, nullptr, qk, vtb, MTOK, 1536, 512, 24, 1024);
    attn_reg<<<dim3(512,1,1), 512, 0, stream>>>(qk, vtb, rnP, mbP, w_edge, OpA, OpB, mlp);
    attn_combine4<<<dim3(512,1,1), 256, 0, stream>>>(OpA, OpB, mlp, ob);
    // x1 = ob @ w_out + b_out + x
    gemm32n<1,false,false,8><<<dim3(512,1,1), 256, 0, stream>>>(
        ob, woutT, b_out, x, x1, MTOK, 512, 512, 16);
    // ---- phase 2 ----
    ln_bf16<<<MTOK, 256, 0, stream>>>(x1, ln2_g, ln2_b, y);
    gemm64<2,true,false,false,8,false><<<dim3(1024,1,1), 256, 0, stream>>>(
        y, w1T, b1, nullptr, hid, nullptr, MTOK, 2048, 512, 32, 2048);
    // out = hid @ w2 + b2 + x1
    gemm32n<1,false,false,32><<<dim3(512,1,1), 256, 0, stream>>>(
        hid, w2T, b2, x1, out, MTOK, 512, 2048, 16);
}